// Round 4
// baseline (243.416 us; speedup 1.0000x reference)
//
#include <hip/hip_runtime.h>
#include <math.h>

#define VOCAB 30000
#define DMODEL 256
#define NHEAD 4
#define SEQ 1024
#define BATCH 16
#define MROWS (BATCH*SEQ)   // 16384
#define SL2 0.18033688011112042f            // 0.125 * log2(e)
#define NEG2 (-1.4426950408889634e10f)      // -1e10 * log2(e)
#define THR2 12.0f

typedef __attribute__((ext_vector_type(8))) short bf16x8;
typedef __attribute__((ext_vector_type(4))) float f32x4;

#if __has_builtin(__builtin_amdgcn_exp2f)
#define EXP2F __builtin_amdgcn_exp2f
#else
#define EXP2F exp2f
#endif

__device__ __forceinline__ unsigned short f2b(float f) {
    unsigned int u = __float_as_uint(f);
    unsigned int r = (u + 0x7FFFu + ((u >> 16) & 1u)) >> 16;
    return (unsigned short)r;
}
__device__ __forceinline__ float b2f(unsigned short s) {
    unsigned int u = ((unsigned int)s) << 16;
    return __uint_as_float(u);
}

// ---------------- positional encoding (f64 math, shared down[] table) ----------------
__global__ void pe2_kernel(float* __restrict__ pe) {
    __shared__ double down[128];
    int t = threadIdx.x;
    if (t < 128) down[t] = exp((double)(2 * t) * (-9.210340371976184 / 256.0));
    __syncthreads();
    int d2 = t & 127, half = t >> 7;
    #pragma unroll
    for (int i = 0; i < 8; i++) {
        int n = blockIdx.x * 16 + half * 8 + i;
        double ang = (double)n * down[d2];
        pe[n * DMODEL + 2 * d2]     = (float)(sin(ang) * 0.1);
        pe[n * DMODEL + 2 * d2 + 1] = (float)(cos(ang) * 0.1);
    }
}

// ---------------- per-batch span from attention_mask ----------------
__global__ void span_kernel(const int* __restrict__ mask, int* __restrict__ spans) {
    int b = blockIdx.x;
    __shared__ int smin, smax;
    if (threadIdx.x == 0) { smin = SEQ; smax = -1; }
    __syncthreads();
    int lmin = SEQ, lmax = -1;
    for (int i = threadIdx.x; i < SEQ; i += 256) {
        if (mask[b * SEQ + i] != 0) { lmin = min(lmin, i); lmax = max(lmax, i); }
    }
    atomicMin(&smin, lmin);
    atomicMax(&smax, lmax);
    __syncthreads();
    if (threadIdx.x == 0) {
        int st, en;
        if (smax < 0) { st = 0; en = SEQ - 1; }
        else          { st = smin; en = smax; }
        spans[b * 2] = st; spans[b * 2 + 1] = en;
    }
}

// ---------------- qkv weight+bias convert (one launch) ----------------
__global__ void cvt_qkv(const float* __restrict__ wq, const float* __restrict__ wk,
                        const float* __restrict__ wv, const float* __restrict__ bq,
                        const float* __restrict__ bk, const float* __restrict__ bv,
                        unsigned short* __restrict__ wqkv, float* __restrict__ bias768) {
    int blk = blockIdx.x;
    if (blk < 768) {
        const float* src = (blk < 256) ? wq : (blk < 512) ? wk : wv;
        wqkv[blk * 256 + threadIdx.x] = f2b(src[(blk & 255) * 256 + threadIdx.x]);
    } else {
        for (int j = threadIdx.x; j < 768; j += 256)
            bias768[j] = (j < 256) ? bq[j] : (j < 512) ? bk[j - 256] : bv[j - 512];
    }
}

// ---------------- fc/ff1/ff2 weight convert (one launch) ----------------
__global__ void cvt3(const float* __restrict__ w0, const float* __restrict__ w1,
                     const float* __restrict__ w2, unsigned short* __restrict__ wb) {
    int blk = blockIdx.x;
    const float* src = (blk < 256) ? w0 : (blk < 512) ? w1 : w2;
    wb[blk * 256 + threadIdx.x] = f2b(src[(blk & 255) * 256 + threadIdx.x]);
}

// ---------------- fused embedding gather + pos enc -> x0b (bf16), no transpose ----------------
__global__ void embed_gather(const int* __restrict__ ids, const float* __restrict__ W,
                             const float* __restrict__ eb, const float* __restrict__ pe,
                             unsigned short* __restrict__ x0b) {
    int bn = blockIdx.x;
    int d = threadIdx.x;
    int id = ids[bn];
    int n = bn & (SEQ - 1);
    float v = W[(size_t)d * VOCAB + id] + eb[d] + pe[n * DMODEL + d];
    x0b[(size_t)bn * DMODEL + d] = f2b(v);
}

// ---------------- bf16 MFMA GEMM: BM=64, BN=128; A(16384x256) @ W^T ----------------
// MODE 0: pooled-partial reduce (no big output)  MODE 2: bf16 out (+bias+residual bf16)
// MODE 3: bf16 out (+bias+gelu)                  MODE 5: fused QKV scatter (Q*SL2; V transposed)
template <int MODE>
__global__ __launch_bounds__(256) void bgemm(const unsigned short* __restrict__ A,
                                             const unsigned short* __restrict__ W,
                                             const float* __restrict__ bias,
                                             const unsigned short* __restrict__ Rres,
                                             void* __restrict__ Cout,
                                             void* __restrict__ Cout2,
                                             void* __restrict__ Cout3) {
    __shared__ unsigned short As[64 * 64];
    __shared__ unsigned short Bs[128 * 64];
    int tid = threadIdx.x;
    int n0 = blockIdx.x * 128, m0 = blockIdx.y * 64;
    int w = tid >> 6, l = tid & 63;
    int wr = (w >> 1) * 32, wc = (w & 1) * 64;
    int lg = l >> 4, ll = l & 15;
    f32x4 acc[2][4] = {};

    for (int k0 = 0; k0 < 256; k0 += 64) {
        __syncthreads();
        #pragma unroll
        for (int i = 0; i < 2; i++) {
            int s = tid + i * 256;            // 0..511
            int row = s >> 3;                 // 0..63
            int kb = (s & 7) * 16;
            int swz = kb ^ ((row & 7) << 4);
            float4 av = *(const float4*)((const char*)A + (size_t)(m0 + row) * 512 + k0 * 2 + kb);
            *(float4*)((char*)As + row * 128 + swz) = av;
        }
        #pragma unroll
        for (int i = 0; i < 4; i++) {
            int s = tid + i * 256;            // 0..1023
            int row = s >> 3;                 // 0..127
            int kb = (s & 7) * 16;
            int swz = kb ^ ((row & 7) << 4);
            float4 bv = *(const float4*)((const char*)W + (size_t)(n0 + row) * 512 + k0 * 2 + kb);
            *(float4*)((char*)Bs + row * 128 + swz) = bv;
        }
        __syncthreads();

        bf16x8 af[2][2], bf[4][2];
        #pragma unroll
        for (int mf = 0; mf < 2; mf++) {
            int row = wr + mf * 16 + ll;
            #pragma unroll
            for (int ks = 0; ks < 2; ks++) {
                int off = (lg * 16 + ks * 64) ^ ((row & 7) << 4);
                af[mf][ks] = *(const bf16x8*)((const char*)As + row * 128 + off);
            }
        }
        #pragma unroll
        for (int nf = 0; nf < 4; nf++) {
            int row = wc + nf * 16 + ll;
            #pragma unroll
            for (int ks = 0; ks < 2; ks++) {
                int off = (lg * 16 + ks * 64) ^ ((row & 7) << 4);
                bf[nf][ks] = *(const bf16x8*)((const char*)Bs + row * 128 + off);
            }
        }
        __builtin_amdgcn_s_setprio(1);
        #pragma unroll
        for (int ks = 0; ks < 2; ks++)
            #pragma unroll
            for (int mf = 0; mf < 2; mf++)
                #pragma unroll
                for (int nf = 0; nf < 4; nf++)
                    acc[mf][nf] = __builtin_amdgcn_mfma_f32_16x16x32_bf16(af[mf][ks], bf[nf][ks], acc[mf][nf], 0, 0, 0);
        __builtin_amdgcn_s_setprio(0);
    }

    float bcol[4];
    #pragma unroll
    for (int nf = 0; nf < 4; nf++) bcol[nf] = bias[n0 + wc + nf * 16 + ll];

    if (MODE == 0) {
        // fused mean-pool partial: sum 32 rows per wave-row-group, write deterministic partials
        int b = m0 >> 10, ib = (m0 >> 6) & 15, g = wr >> 5;
        #pragma unroll
        for (int nf = 0; nf < 4; nf++) {
            float s = 0.f;
            #pragma unroll
            for (int mf = 0; mf < 2; mf++)
                #pragma unroll
                for (int r = 0; r < 4; r++)
                    s += acc[mf][nf][r];
            s += 8.f * bcol[nf];
            s += __shfl_xor(s, 16);
            s += __shfl_xor(s, 32);
            if (lg == 0) {
                int n = n0 + wc + nf * 16 + ll;
                ((float*)Cout)[((size_t)b * 32 + ib * 2 + g) * 256 + n] = s;
            }
        }
        return;
    }

    #pragma unroll
    for (int mf = 0; mf < 2; mf++) {
        #pragma unroll
        for (int r = 0; r < 4; r++) {
            int m = m0 + wr + mf * 16 + lg * 4 + r;
            #pragma unroll
            for (int nf = 0; nf < 4; nf++) {
                int n = n0 + wc + nf * 16 + ll;
                float v = acc[mf][nf][r] + bcol[nf];
                if (MODE == 2) v += b2f(Rres[(size_t)m * 256 + n]);
                if (MODE == 3) v = 0.5f * v * (1.f + erff(v * 0.70710678118654752f));
                if (MODE == 5) {
                    int which = n >> 8, e = n & 255, hh = e >> 6, dk = e & 63;
                    int bb = m >> 10, ns = m & 1023;
                    if (which == 0)
                        ((unsigned short*)Cout)[((((size_t)bb * 4 + hh) * 1024) + ns) * 64 + dk] = f2b(v * SL2);
                    else if (which == 1)
                        ((unsigned short*)Cout2)[((((size_t)bb * 4 + hh) * 1024) + ns) * 64 + dk] = f2b(v);
                    else
                        ((unsigned short*)Cout3)[((((size_t)bb * 4 + hh) * 64) + dk) * 1024 + ns] = f2b(v);
                } else {
                    ((unsigned short*)Cout)[(size_t)m * 256 + n] = f2b(v);
                }
            }
        }
    }
}

// ---------------- K/V fragment loaders (direct global, L2-resident) ----------------
__device__ __forceinline__ void ldk(const char* kbase, int kv0, bf16x8 (&f)[4][2]) {
    #pragma unroll
    for (int nf = 0; nf < 4; nf++)
        #pragma unroll
        for (int ks = 0; ks < 2; ks++)
            f[nf][ks] = *(const bf16x8*)(kbase + (size_t)kv0 * 128 + nf * 2048 + ks * 64);
}
__device__ __forceinline__ void ldv(const char* vbase, int kv0, bf16x8 (&f)[4][2]) {
    #pragma unroll
    for (int cf = 0; cf < 4; cf++)
        #pragma unroll
        for (int ks = 0; ks < 2; ks++)
            f[cf][ks] = *(const bf16x8*)(vbase + (size_t)cf * 32768 + kv0 * 2 + ks * 64);
}

// ---------------- bf16 MFMA flash attention, 1 wave/32 q-rows, prefetch + XCD swizzle ----------------
__global__ __launch_bounds__(64) void attn_mfma(const unsigned short* __restrict__ Qb,
                                                const unsigned short* __restrict__ Kb,
                                                const unsigned short* __restrict__ Vt,
                                                const int* __restrict__ spans,
                                                unsigned short* __restrict__ attb) {
    __shared__ __align__(16) unsigned short Ps[32 * 72];
    // XCD swizzle: all 32 q-blocks of one (b,h) share one XCD class (id & 7)
    int id = blockIdx.x;
    int c = id & 7, r = id >> 3;
    int bh = c * 8 + (r >> 5);
    int q0 = (r & 31) * 32;
    int b = bh >> 2, h = bh & 3;
    int l = threadIdx.x;
    int lg = l >> 4, ll = l & 15;
    const char* Kp = (const char*)(Kb + (size_t)bh * SEQ * 64);
    const char* Vp = (const char*)(Vt + (size_t)bh * 64 * SEQ);
    const unsigned short* Qp = Qb + (size_t)bh * SEQ * 64;
    int start = spans[b * 2], end = spans[b * 2 + 1];

    bf16x8 qf[2][2];
    #pragma unroll
    for (int mf = 0; mf < 2; mf++)
        #pragma unroll
        for (int ks = 0; ks < 2; ks++)
            qf[mf][ks] = *(const bf16x8*)(Qp + (size_t)(q0 + mf * 16 + ll) * 64 + lg * 8 + ks * 32);

    f32x4 o[2][4] = {};
    float mrow[2][4], lrow[2][4];
    bool rowok[2][4];
    #pragma unroll
    for (int mf = 0; mf < 2; mf++)
        #pragma unroll
        for (int r2 = 0; r2 < 4; r2++) {
            mrow[mf][r2] = -INFINITY; lrow[mf][r2] = 0.f;
            int rr = q0 + mf * 16 + lg * 4 + r2;
            rowok[mf][r2] = (rr >= start) && (rr < end);
        }

    const char* kbase = Kp + (size_t)ll * 128 + lg * 16;
    const char* vbase = Vp + (size_t)ll * 2048 + lg * 16;

    bf16x8 kf[4][2], kn[4][2], vf[4][2];
    ldk(kbase, 0, kf);

    for (int ct = 0; ct < 16; ct++) {
        int kv0 = ct * 64;
        // prefetch: V of this tile (used after softmax), K of next tile (used next iter)
        ldv(vbase, kv0, vf);
        if (ct < 15) ldk(kbase, kv0 + 64, kn);

        f32x4 s[2][4] = {};
        __builtin_amdgcn_s_setprio(1);
        #pragma unroll
        for (int ks = 0; ks < 2; ks++)
            #pragma unroll
            for (int mf = 0; mf < 2; mf++)
                #pragma unroll
                for (int nf = 0; nf < 4; nf++)
                    s[mf][nf] = __builtin_amdgcn_mfma_f32_16x16x32_bf16(qf[mf][ks], kf[nf][ks], s[mf][nf], 0, 0, 0);
        __builtin_amdgcn_s_setprio(0);

        bool colok[4];
        #pragma unroll
        for (int nf = 0; nf < 4; nf++) {
            int cc = kv0 + nf * 16 + ll;
            colok[nf] = (cc >= start) && (cc < end);
        }
        #pragma unroll
        for (int mf = 0; mf < 2; mf++)
            #pragma unroll
            for (int nf = 0; nf < 4; nf++)
                #pragma unroll
                for (int r2 = 0; r2 < 4; r2++)
                    if (!(rowok[mf][r2] && colok[nf])) s[mf][nf][r2] += NEG2;

        float mt[2][4];
        #pragma unroll
        for (int mf = 0; mf < 2; mf++)
            #pragma unroll
            for (int r2 = 0; r2 < 4; r2++)
                mt[mf][r2] = fmaxf(fmaxf(s[mf][0][r2], s[mf][1][r2]), fmaxf(s[mf][2][r2], s[mf][3][r2]));
        #pragma unroll
        for (int off = 1; off < 16; off <<= 1)
            #pragma unroll
            for (int mf = 0; mf < 2; mf++)
                #pragma unroll
                for (int r2 = 0; r2 < 4; r2++)
                    mt[mf][r2] = fmaxf(mt[mf][r2], __shfl_xor(mt[mf][r2], off));

        bool ex = false;
        #pragma unroll
        for (int mf = 0; mf < 2; mf++)
            #pragma unroll
            for (int r2 = 0; r2 < 4; r2++)
                ex = ex || (mt[mf][r2] > mrow[mf][r2] + THR2);
        if (__any(ex)) {
            #pragma unroll
            for (int mf = 0; mf < 2; mf++)
                #pragma unroll
                for (int r2 = 0; r2 < 4; r2++) {
                    float mnew = fmaxf(mrow[mf][r2], mt[mf][r2]);
                    float alpha = EXP2F(mrow[mf][r2] - mnew);
                    mrow[mf][r2] = mnew;
                    lrow[mf][r2] *= alpha;
                    #pragma unroll
                    for (int cf = 0; cf < 4; cf++)
                        o[mf][cf][r2] *= alpha;
                }
        }

        float rs[2][4];
        #pragma unroll
        for (int mf = 0; mf < 2; mf++)
            #pragma unroll
            for (int r2 = 0; r2 < 4; r2++) {
                float acc_rs = 0.f;
                #pragma unroll
                for (int nf = 0; nf < 4; nf++) {
                    float p = EXP2F(s[mf][nf][r2] - mrow[mf][r2]);
                    s[mf][nf][r2] = p;
                    acc_rs += p;
                }
                rs[mf][r2] = acc_rs;
            }
        #pragma unroll
        for (int off = 1; off < 16; off <<= 1)
            #pragma unroll
            for (int mf = 0; mf < 2; mf++)
                #pragma unroll
                for (int r2 = 0; r2 < 4; r2++)
                    rs[mf][r2] += __shfl_xor(rs[mf][r2], off);
        #pragma unroll
        for (int mf = 0; mf < 2; mf++)
            #pragma unroll
            for (int r2 = 0; r2 < 4; r2++)
                lrow[mf][r2] += rs[mf][r2];

        // P -> per-wave LDS (bf16) for A-fragment relayout (no barrier: single wave)
        #pragma unroll
        for (int mf = 0; mf < 2; mf++)
            #pragma unroll
            for (int nf = 0; nf < 4; nf++)
                #pragma unroll
                for (int r2 = 0; r2 < 4; r2++)
                    Ps[(mf * 16 + lg * 4 + r2) * 72 + nf * 16 + ll] = f2b(s[mf][nf][r2]);

        bf16x8 pa[2][2];
        #pragma unroll
        for (int rf = 0; rf < 2; rf++) {
            int row = rf * 16 + ll;
            #pragma unroll
            for (int ks = 0; ks < 2; ks++)
                pa[rf][ks] = *(const bf16x8*)(&Ps[row * 72 + lg * 8 + ks * 32]);
        }
        __builtin_amdgcn_s_setprio(1);
        #pragma unroll
        for (int ks = 0; ks < 2; ks++)
            #pragma unroll
            for (int rf = 0; rf < 2; rf++)
                #pragma unroll
                for (int cf = 0; cf < 4; cf++)
                    o[rf][cf] = __builtin_amdgcn_mfma_f32_16x16x32_bf16(pa[rf][ks], vf[cf][ks], o[rf][cf], 0, 0, 0);
        __builtin_amdgcn_s_setprio(0);

        #pragma unroll
        for (int nf = 0; nf < 4; nf++)
            #pragma unroll
            for (int ks = 0; ks < 2; ks++)
                kf[nf][ks] = kn[nf][ks];
    }

    #pragma unroll
    for (int rf = 0; rf < 2; rf++)
        #pragma unroll
        for (int r2 = 0; r2 < 4; r2++) {
            float inv = 1.f / lrow[rf][r2];
            int row = q0 + rf * 16 + lg * 4 + r2;
            #pragma unroll
            for (int cf = 0; cf < 4; cf++) {
                int dk = cf * 16 + ll;
                attb[((size_t)b * SEQ + row) * 256 + h * 64 + dk] = f2b(o[rf][cf][r2] * inv);
            }
        }
}

// ---------------- fused pool stage 2 + MLP head (eval BatchNorm) ----------------
__global__ __launch_bounds__(128) void head2_kernel(const float* __restrict__ part,
                                                    const float* __restrict__ h1_w, const float* __restrict__ h1_b,
                                                    const float* __restrict__ g, const float* __restrict__ be,
                                                    const float* __restrict__ mu, const float* __restrict__ var,
                                                    const float* __restrict__ h2_w, const float* __restrict__ h2_b,
                                                    float* __restrict__ out) {
    int b = blockIdx.x, j = threadIdx.x;
    __shared__ float pl[256];
    __shared__ float red[128];
    float s0 = 0.f, s1 = 0.f;
    for (int ch = 0; ch < 32; ch++) {
        s0 += part[((size_t)b * 32 + ch) * 256 + j];
        s1 += part[((size_t)b * 32 + ch) * 256 + j + 128];
    }
    pl[j] = s0 * (1.f / 1024.f);
    pl[j + 128] = s1 * (1.f / 1024.f);
    __syncthreads();
    float s = 0.f;
    for (int d = 0; d < 256; d++) s = fmaf(pl[d], h1_w[j * 256 + d], s);
    s += h1_b[j];
    s = (s - mu[j]) / sqrtf(var[j] + 1e-5f) * g[j] + be[j];
    s = fmaxf(s, 0.f);
    red[j] = s * h2_w[j];
    __syncthreads();
    for (int off = 64; off; off >>= 1) {
        if (j < off) red[j] += red[j + off];
        __syncthreads();
    }
    if (j == 0) out[b] = red[0] + h2_b[0];
}

// ---------------- launch ----------------
extern "C" void kernel_launch(void* const* d_in, const int* in_sizes, int n_in,
                              void* d_out, int out_size, void* d_ws, size_t ws_size,
                              hipStream_t stream) {
    (void)in_sizes; (void)n_in; (void)out_size; (void)ws_size;
    const int*   ids    = (const int*)d_in[0];
    const int*   amask  = (const int*)d_in[1];
    const float* emb_W  = (const float*)d_in[2];
    const float* emb_b  = (const float*)d_in[3];
    const float* wq = (const float*)d_in[4],  *bq = (const float*)d_in[5];
    const float* wk = (const float*)d_in[6],  *bk = (const float*)d_in[7];
    const float* wv = (const float*)d_in[8],  *bv = (const float*)d_in[9];
    const float* fcw = (const float*)d_in[10], *fcb = (const float*)d_in[11];
    const float* f1w = (const float*)d_in[12], *f1b = (const float*)d_in[13];
    const float* f2w = (const float*)d_in[14], *f2b_ = (const float*)d_in[15];
    const float* h1w = (const float*)d_in[16], *h1b = (const float*)d_in[17];
    const float* bng = (const float*)d_in[18], *bnb = (const float*)d_in[19];
    const float* bnm = (const float*)d_in[20], *bnv = (const float*)d_in[21];
    const float* h2w = (const float*)d_in[22], *h2b = (const float*)d_in[23];
    float* out = (float*)d_out;
    float* ws = (float*)d_ws;

    // workspace layout (float units)
    const size_t O_PE   = 0;                        // 262,144
    const size_t O_X0B  = O_PE + 262144;            // 2,097,152 (bf16 16384x256)
    const size_t O_Q    = O_X0B + 2097152;          // 2,097,152
    const size_t O_K    = O_Q + 2097152;            // 2,097,152
    const size_t O_V    = O_K + 2097152;            // 2,097,152
    const size_t O_ATT  = O_V + 2097152;            // 2,097,152
    const size_t O_X1B  = O_ATT + 2097152;          // 2,097,152
    const size_t O_HB   = O_X1B + 2097152;          // 2,097,152
    const size_t O_WQKV = O_HB + 2097152;           // 98,304 (768x256 shorts)
    const size_t O_WB3  = O_WQKV + 98304;           // 98,304
    const size_t O_B768 = O_WB3 + 98304;            // 768
    const size_t O_PART = O_B768 + 768;             // 131,072 (16x32x256 f32)
    const size_t O_SPAN = O_PART + 131072;

    float* pe   = ws + O_PE;
    unsigned short* x0b  = (unsigned short*)(ws + O_X0B);
    unsigned short* Qb   = (unsigned short*)(ws + O_Q);
    unsigned short* Kb   = (unsigned short*)(ws + O_K);
    unsigned short* Vt   = (unsigned short*)(ws + O_V);
    unsigned short* attb = (unsigned short*)(ws + O_ATT);
    unsigned short* x1b  = (unsigned short*)(ws + O_X1B);
    unsigned short* hb   = (unsigned short*)(ws + O_HB);
    unsigned short* wqkv = (unsigned short*)(ws + O_WQKV);
    unsigned short* wb3  = (unsigned short*)(ws + O_WB3);
    float* bias768 = ws + O_B768;
    float* part = ws + O_PART;
    int* spans  = (int*)(ws + O_SPAN);

    pe2_kernel<<<64, 256, 0, stream>>>(pe);
    span_kernel<<<BATCH, 256, 0, stream>>>(amask, spans);
    cvt_qkv<<<769, 256, 0, stream>>>(wq, wk, wv, bq, bk, bv, wqkv, bias768);
    cvt3<<<768, 256, 0, stream>>>(fcw, f1w, f2w, wb3);
    embed_gather<<<MROWS, 256, 0, stream>>>(ids, emb_W, emb_b, pe, x0b);

    // fused QKV: N=768, BM=64 -> grid (6,256)
    bgemm<5><<<dim3(6, 256), 256, 0, stream>>>(x0b, wqkv, bias768, nullptr, Qb, Kb, Vt);

    attn_mfma<<<2048, 64, 0, stream>>>(Qb, Kb, Vt, spans, attb);

    dim3 gg(2, 256);
    bgemm<2><<<gg, 256, 0, stream>>>(attb, wb3 + 0 * 65536, fcb, x0b, x1b, nullptr, nullptr);
    bgemm<3><<<gg, 256, 0, stream>>>(x1b,  wb3 + 1 * 65536, f1b, nullptr, hb, nullptr, nullptr);
    bgemm<0><<<gg, 256, 0, stream>>>(hb,   wb3 + 2 * 65536, f2b_, nullptr, part, nullptr, nullptr);

    head2_kernel<<<BATCH, 128, 0, stream>>>(part, h1w, h1b, bng, bnb, bnm, bnv, h2w, h2b, out);
}

// Round 5
// 173.778 us; speedup vs baseline: 1.4007x; 1.4007x over previous
//
#include <hip/hip_runtime.h>
#include <math.h>

#define VOCAB 30000
#define DMODEL 256
#define NHEAD 4
#define SEQ 1024
#define BATCH 16
#define MROWS (BATCH*SEQ)   // 16384
#define SL2 0.18033688011112042f            // 0.125 * log2(e)
#define NEG2 (-1.4426950408889634e10f)      // -1e10 * log2(e)
#define THR2 12.0f

typedef __attribute__((ext_vector_type(8))) short bf16x8;
typedef __attribute__((ext_vector_type(4))) float f32x4;

#if __has_builtin(__builtin_amdgcn_exp2f)
#define EXP2F __builtin_amdgcn_exp2f
#else
#define EXP2F exp2f
#endif

__device__ __forceinline__ unsigned short f2b(float f) {
    unsigned int u = __float_as_uint(f);
    unsigned int r = (u + 0x7FFFu + ((u >> 16) & 1u)) >> 16;
    return (unsigned short)r;
}
__device__ __forceinline__ float b2f(unsigned short s) {
    unsigned int u = ((unsigned int)s) << 16;
    return __uint_as_float(u);
}

// ---------------- transpose W (D x V) -> bf16 embT (V x D), emb_b folded ----------------
__global__ void transpose_b(const float* __restrict__ in, const float* __restrict__ eb,
                            unsigned short* __restrict__ outb) {
    __shared__ float t[32][33];
    int c0 = blockIdx.x * 32, r0 = blockIdx.y * 32;   // c: vocab, r: d
    int tx = threadIdx.x, ty = threadIdx.y;           // 32 x 8
    for (int i = 0; i < 32; i += 8) {
        int r = r0 + ty + i, c = c0 + tx;
        if (c < VOCAB) t[ty + i][tx] = in[(size_t)r * VOCAB + c];
    }
    __syncthreads();
    float ebv = eb[r0 + tx];
    for (int i = 0; i < 32; i += 8) {
        int c = c0 + ty + i, r = r0 + tx;
        if (c < VOCAB) outb[(size_t)c * DMODEL + r] = f2b(t[tx][ty + i] + ebv);
    }
}

// ---------------- positional encoding (f64 math, shared down[] table) ----------------
__global__ void pe2_kernel(float* __restrict__ pe) {
    __shared__ double down[128];
    int t = threadIdx.x;
    if (t < 128) down[t] = exp((double)(2 * t) * (-9.210340371976184 / 256.0));
    __syncthreads();
    int d2 = t & 127, half = t >> 7;
    #pragma unroll
    for (int i = 0; i < 8; i++) {
        int n = blockIdx.x * 16 + half * 8 + i;
        double ang = (double)n * down[d2];
        pe[n * DMODEL + 2 * d2]     = (float)(sin(ang) * 0.1);
        pe[n * DMODEL + 2 * d2 + 1] = (float)(cos(ang) * 0.1);
    }
}

// ---------------- per-batch span from attention_mask ----------------
__global__ void span_kernel(const int* __restrict__ mask, int* __restrict__ spans) {
    int b = blockIdx.x;
    __shared__ int smin, smax;
    if (threadIdx.x == 0) { smin = SEQ; smax = -1; }
    __syncthreads();
    int lmin = SEQ, lmax = -1;
    for (int i = threadIdx.x; i < SEQ; i += 256) {
        if (mask[b * SEQ + i] != 0) { lmin = min(lmin, i); lmax = max(lmax, i); }
    }
    atomicMin(&smin, lmin);
    atomicMax(&smax, lmax);
    __syncthreads();
    if (threadIdx.x == 0) {
        int st, en;
        if (smax < 0) { st = 0; en = SEQ - 1; }
        else          { st = smin; en = smax; }
        spans[b * 2] = st; spans[b * 2 + 1] = en;
    }
}

// ---------------- qkv weight+bias convert ----------------
__global__ void cvt_qkv(const float* __restrict__ wq, const float* __restrict__ wk,
                        const float* __restrict__ wv, const float* __restrict__ bq,
                        const float* __restrict__ bk, const float* __restrict__ bv,
                        unsigned short* __restrict__ wqkv, float* __restrict__ bias768) {
    int blk = blockIdx.x;
    if (blk < 768) {
        const float* src = (blk < 256) ? wq : (blk < 512) ? wk : wv;
        wqkv[blk * 256 + threadIdx.x] = f2b(src[(blk & 255) * 256 + threadIdx.x]);
    } else {
        for (int j = threadIdx.x; j < 768; j += 256)
            bias768[j] = (j < 256) ? bq[j] : (j < 512) ? bk[j - 256] : bv[j - 512];
    }
}

// ---------------- fc/ff1/ff2 weight convert ----------------
__global__ void cvt3(const float* __restrict__ w0, const float* __restrict__ w1,
                     const float* __restrict__ w2, unsigned short* __restrict__ wb) {
    int blk = blockIdx.x;
    const float* src = (blk < 256) ? w0 : (blk < 512) ? w1 : w2;
    wb[blk * 256 + threadIdx.x] = f2b(src[(blk & 255) * 256 + threadIdx.x]);
}

// ---------------- embedding gather (coalesced bf16 rows) + pos enc ----------------
__global__ void embed_kernel(const int* __restrict__ ids, const unsigned short* __restrict__ embT,
                             const float* __restrict__ pe, unsigned short* __restrict__ x0b) {
    int bn = blockIdx.x;
    int d = threadIdx.x;
    int id = ids[bn];
    int n = bn & (SEQ - 1);
    float v = b2f(embT[(size_t)id * DMODEL + d]) + pe[n * DMODEL + d];
    x0b[(size_t)bn * DMODEL + d] = f2b(v);
}

// ---------------- bf16 MFMA GEMM: BM=64, BN=128; A(16384x256) @ W^T ----------------
// MODE 0: pooled-partial reduce   MODE 2: bf16 out (+bias+residual bf16)
// MODE 3: bf16 out (+bias+gelu)   MODE 5: fused QKV scatter (Q*SL2; V transposed)
template <int MODE>
__global__ __launch_bounds__(256) void bgemm(const unsigned short* __restrict__ A,
                                             const unsigned short* __restrict__ W,
                                             const float* __restrict__ bias,
                                             const unsigned short* __restrict__ Rres,
                                             void* __restrict__ Cout,
                                             void* __restrict__ Cout2,
                                             void* __restrict__ Cout3) {
    __shared__ unsigned short As[64 * 64];
    __shared__ unsigned short Bs[128 * 64];
    int tid = threadIdx.x;
    int n0 = blockIdx.x * 128, m0 = blockIdx.y * 64;
    int w = tid >> 6, l = tid & 63;
    int wr = (w >> 1) * 32, wc = (w & 1) * 64;
    int lg = l >> 4, ll = l & 15;
    f32x4 acc[2][4] = {};

    for (int k0 = 0; k0 < 256; k0 += 64) {
        __syncthreads();
        #pragma unroll
        for (int i = 0; i < 2; i++) {
            int s = tid + i * 256;
            int row = s >> 3;
            int kb = (s & 7) * 16;
            int swz = kb ^ ((row & 7) << 4);
            float4 av = *(const float4*)((const char*)A + (size_t)(m0 + row) * 512 + k0 * 2 + kb);
            *(float4*)((char*)As + row * 128 + swz) = av;
        }
        #pragma unroll
        for (int i = 0; i < 4; i++) {
            int s = tid + i * 256;
            int row = s >> 3;
            int kb = (s & 7) * 16;
            int swz = kb ^ ((row & 7) << 4);
            float4 bv = *(const float4*)((const char*)W + (size_t)(n0 + row) * 512 + k0 * 2 + kb);
            *(float4*)((char*)Bs + row * 128 + swz) = bv;
        }
        __syncthreads();

        bf16x8 af[2][2], bf[4][2];
        #pragma unroll
        for (int mf = 0; mf < 2; mf++) {
            int row = wr + mf * 16 + ll;
            #pragma unroll
            for (int ks = 0; ks < 2; ks++) {
                int off = (lg * 16 + ks * 64) ^ ((row & 7) << 4);
                af[mf][ks] = *(const bf16x8*)((const char*)As + row * 128 + off);
            }
        }
        #pragma unroll
        for (int nf = 0; nf < 4; nf++) {
            int row = wc + nf * 16 + ll;
            #pragma unroll
            for (int ks = 0; ks < 2; ks++) {
                int off = (lg * 16 + ks * 64) ^ ((row & 7) << 4);
                bf[nf][ks] = *(const bf16x8*)((const char*)Bs + row * 128 + off);
            }
        }
        #pragma unroll
        for (int ks = 0; ks < 2; ks++)
            #pragma unroll
            for (int mf = 0; mf < 2; mf++)
                #pragma unroll
                for (int nf = 0; nf < 4; nf++)
                    acc[mf][nf] = __builtin_amdgcn_mfma_f32_16x16x32_bf16(af[mf][ks], bf[nf][ks], acc[mf][nf], 0, 0, 0);
    }

    float bcol[4];
    #pragma unroll
    for (int nf = 0; nf < 4; nf++) bcol[nf] = bias[n0 + wc + nf * 16 + ll];

    if (MODE == 0) {
        int b = m0 >> 10, ib = (m0 >> 6) & 15, g = wr >> 5;
        #pragma unroll
        for (int nf = 0; nf < 4; nf++) {
            float s = 0.f;
            #pragma unroll
            for (int mf = 0; mf < 2; mf++)
                #pragma unroll
                for (int r = 0; r < 4; r++)
                    s += acc[mf][nf][r];
            s += 8.f * bcol[nf];
            s += __shfl_xor(s, 16);
            s += __shfl_xor(s, 32);
            if (lg == 0) {
                int n = n0 + wc + nf * 16 + ll;
                ((float*)Cout)[((size_t)b * 32 + ib * 2 + g) * 256 + n] = s;
            }
        }
        return;
    }

    #pragma unroll
    for (int mf = 0; mf < 2; mf++) {
        #pragma unroll
        for (int r = 0; r < 4; r++) {
            int m = m0 + wr + mf * 16 + lg * 4 + r;
            #pragma unroll
            for (int nf = 0; nf < 4; nf++) {
                int n = n0 + wc + nf * 16 + ll;
                float v = acc[mf][nf][r] + bcol[nf];
                if (MODE == 2) v += b2f(Rres[(size_t)m * 256 + n]);
                if (MODE == 3) v = 0.5f * v * (1.f + erff(v * 0.70710678118654752f));
                if (MODE == 5) {
                    int which = n >> 8, e = n & 255, hh = e >> 6, dk = e & 63;
                    int bb = m >> 10, ns = m & 1023;
                    if (which == 0)
                        ((unsigned short*)Cout)[((((size_t)bb * 4 + hh) * 1024) + ns) * 64 + dk] = f2b(v * SL2);
                    else if (which == 1)
                        ((unsigned short*)Cout2)[((((size_t)bb * 4 + hh) * 1024) + ns) * 64 + dk] = f2b(v);
                    else
                        ((unsigned short*)Cout3)[((((size_t)bb * 4 + hh) * 64) + dk) * 1024 + ns] = f2b(v);
                } else {
                    ((unsigned short*)Cout)[(size_t)m * 256 + n] = f2b(v);
                }
            }
        }
    }
}

// ---------------- split-KV bf16 MFMA flash attention ----------------
// grid 4096 x 64 threads: (xcd-swizzled) -> (bh, qb, sp); each block does 8 KV tiles,
// writes normalized partial o (bf16) + m,l (f32). No barriers, 1 wave/block.
__global__ __launch_bounds__(64) void attn_split(const unsigned short* __restrict__ Qb,
                                                 const unsigned short* __restrict__ Kb,
                                                 const unsigned short* __restrict__ Vt,
                                                 const int* __restrict__ spans,
                                                 unsigned short* __restrict__ Op,
                                                 float* __restrict__ ML) {
    __shared__ __align__(16) unsigned short Ps[32 * 72];
    int id = blockIdx.x;
    int xcd = id & 7, j = id >> 3;
    int bh = xcd * 8 + (j >> 6);
    int rem = j & 63;
    int qb = rem >> 1, sp = rem & 1;
    int q0 = qb * 32;
    int b = bh >> 2;
    int l = threadIdx.x;
    int lg = l >> 4, ll = l & 15;
    const char* Kp = (const char*)(Kb + (size_t)bh * SEQ * 64);
    const char* Vp = (const char*)(Vt + (size_t)bh * 64 * SEQ);
    const unsigned short* Qp = Qb + (size_t)bh * SEQ * 64;
    int start = spans[b * 2], end = spans[b * 2 + 1];

    bf16x8 qf[2][2];
    #pragma unroll
    for (int mf = 0; mf < 2; mf++)
        #pragma unroll
        for (int ks = 0; ks < 2; ks++)
            qf[mf][ks] = *(const bf16x8*)(Qp + (size_t)(q0 + mf * 16 + ll) * 64 + lg * 8 + ks * 32);

    f32x4 o[2][4] = {};
    float mrow[2][4], lrow[2][4];
    bool rowok[2][4];
    #pragma unroll
    for (int mf = 0; mf < 2; mf++)
        #pragma unroll
        for (int r2 = 0; r2 < 4; r2++) {
            mrow[mf][r2] = -INFINITY; lrow[mf][r2] = 0.f;
            int rr = q0 + mf * 16 + lg * 4 + r2;
            rowok[mf][r2] = (rr >= start) && (rr < end);
        }

    const char* kbase = Kp + (size_t)ll * 128 + lg * 16;
    const char* vbase = Vp + (size_t)ll * 2048 + lg * 16;

    for (int ct = 0; ct < 8; ct++) {
        int kv0 = sp * 512 + ct * 64;

        bf16x8 kf[4][2];
        #pragma unroll
        for (int nf = 0; nf < 4; nf++)
            #pragma unroll
            for (int ks = 0; ks < 2; ks++)
                kf[nf][ks] = *(const bf16x8*)(kbase + (size_t)kv0 * 128 + nf * 2048 + ks * 64);

        f32x4 s[2][4] = {};
        __builtin_amdgcn_s_setprio(1);
        #pragma unroll
        for (int ks = 0; ks < 2; ks++)
            #pragma unroll
            for (int mf = 0; mf < 2; mf++)
                #pragma unroll
                for (int nf = 0; nf < 4; nf++)
                    s[mf][nf] = __builtin_amdgcn_mfma_f32_16x16x32_bf16(qf[mf][ks], kf[nf][ks], s[mf][nf], 0, 0, 0);
        __builtin_amdgcn_s_setprio(0);

        bool colok[4];
        #pragma unroll
        for (int nf = 0; nf < 4; nf++) {
            int cc = kv0 + nf * 16 + ll;
            colok[nf] = (cc >= start) && (cc < end);
        }
        #pragma unroll
        for (int mf = 0; mf < 2; mf++)
            #pragma unroll
            for (int nf = 0; nf < 4; nf++)
                #pragma unroll
                for (int r2 = 0; r2 < 4; r2++)
                    if (!(rowok[mf][r2] && colok[nf])) s[mf][nf][r2] += NEG2;

        float mt[2][4];
        #pragma unroll
        for (int mf = 0; mf < 2; mf++)
            #pragma unroll
            for (int r2 = 0; r2 < 4; r2++)
                mt[mf][r2] = fmaxf(fmaxf(s[mf][0][r2], s[mf][1][r2]), fmaxf(s[mf][2][r2], s[mf][3][r2]));
        #pragma unroll
        for (int off = 1; off < 16; off <<= 1)
            #pragma unroll
            for (int mf = 0; mf < 2; mf++)
                #pragma unroll
                for (int r2 = 0; r2 < 4; r2++)
                    mt[mf][r2] = fmaxf(mt[mf][r2], __shfl_xor(mt[mf][r2], off));

        bool ex = false;
        #pragma unroll
        for (int mf = 0; mf < 2; mf++)
            #pragma unroll
            for (int r2 = 0; r2 < 4; r2++)
                ex = ex || (mt[mf][r2] > mrow[mf][r2] + THR2);
        if (__any(ex)) {
            #pragma unroll
            for (int mf = 0; mf < 2; mf++)
                #pragma unroll
                for (int r2 = 0; r2 < 4; r2++) {
                    float mnew = fmaxf(mrow[mf][r2], mt[mf][r2]);
                    float alpha = EXP2F(mrow[mf][r2] - mnew);
                    mrow[mf][r2] = mnew;
                    lrow[mf][r2] *= alpha;
                    #pragma unroll
                    for (int cf = 0; cf < 4; cf++)
                        o[mf][cf][r2] *= alpha;
                }
        }

        float rs[2][4];
        #pragma unroll
        for (int mf = 0; mf < 2; mf++)
            #pragma unroll
            for (int r2 = 0; r2 < 4; r2++) {
                float acc_rs = 0.f;
                #pragma unroll
                for (int nf = 0; nf < 4; nf++) {
                    float p = EXP2F(s[mf][nf][r2] - mrow[mf][r2]);
                    s[mf][nf][r2] = p;
                    acc_rs += p;
                }
                rs[mf][r2] = acc_rs;
            }
        #pragma unroll
        for (int off = 1; off < 16; off <<= 1)
            #pragma unroll
            for (int mf = 0; mf < 2; mf++)
                #pragma unroll
                for (int r2 = 0; r2 < 4; r2++)
                    rs[mf][r2] += __shfl_xor(rs[mf][r2], off);
        #pragma unroll
        for (int mf = 0; mf < 2; mf++)
            #pragma unroll
            for (int r2 = 0; r2 < 4; r2++)
                lrow[mf][r2] += rs[mf][r2];

        // P -> per-wave LDS (bf16) for A-fragment relayout (single wave, no barrier)
        #pragma unroll
        for (int mf = 0; mf < 2; mf++)
            #pragma unroll
            for (int nf = 0; nf < 4; nf++)
                #pragma unroll
                for (int r2 = 0; r2 < 4; r2++)
                    Ps[(mf * 16 + lg * 4 + r2) * 72 + nf * 16 + ll] = f2b(s[mf][nf][r2]);

        bf16x8 pa[2][2], vf[4][2];
        #pragma unroll
        for (int rf = 0; rf < 2; rf++) {
            int row = rf * 16 + ll;
            #pragma unroll
            for (int ks = 0; ks < 2; ks++)
                pa[rf][ks] = *(const bf16x8*)(&Ps[row * 72 + lg * 8 + ks * 32]);
        }
        #pragma unroll
        for (int cf = 0; cf < 4; cf++)
            #pragma unroll
            for (int ks = 0; ks < 2; ks++)
                vf[cf][ks] = *(const bf16x8*)(vbase + (size_t)cf * 32768 + kv0 * 2 + ks * 64);
        __builtin_amdgcn_s_setprio(1);
        #pragma unroll
        for (int ks = 0; ks < 2; ks++)
            #pragma unroll
            for (int rf = 0; rf < 2; rf++)
                #pragma unroll
                for (int cf = 0; cf < 4; cf++)
                    o[rf][cf] = __builtin_amdgcn_mfma_f32_16x16x32_bf16(pa[rf][ks], vf[cf][ks], o[rf][cf], 0, 0, 0);
        __builtin_amdgcn_s_setprio(0);
    }

    // write partial: normalized o (bf16) + m,l (f32)
    size_t idx = ((size_t)(bh * 32 + qb)) * 2 + sp;
    #pragma unroll
    for (int rf = 0; rf < 2; rf++)
        #pragma unroll
        for (int r2 = 0; r2 < 4; r2++) {
            int rl = rf * 16 + lg * 4 + r2;
            float inv = 1.f / lrow[rf][r2];
            #pragma unroll
            for (int cf = 0; cf < 4; cf++)
                Op[idx * 2048 + rl * 64 + cf * 16 + ll] = f2b(o[rf][cf][r2] * inv);
            if (ll == 0) {
                ML[idx * 64 + rl] = mrow[rf][r2];
                ML[idx * 64 + 32 + rl] = lrow[rf][r2];
            }
        }
}

// ---------------- combine 2 splits -> attb (B,N,256) bf16 ----------------
__global__ __launch_bounds__(64) void attn_combine(const unsigned short* __restrict__ Op,
                                                   const float* __restrict__ ML,
                                                   unsigned short* __restrict__ attb) {
    int cid = blockIdx.x;              // bh*32 + qb
    int bh = cid >> 5, qb = cid & 31;
    int b = bh >> 2, h = bh & 3;
    int t = threadIdx.x;
    int r = t >> 1, hd = (t & 1) * 32;
    size_t i0 = (size_t)cid * 2;
    float m1 = ML[i0 * 64 + r],       l1 = ML[i0 * 64 + 32 + r];
    float m2 = ML[(i0 + 1) * 64 + r], l2 = ML[(i0 + 1) * 64 + 32 + r];
    float M = fmaxf(m1, m2);
    float w1 = EXP2F(m1 - M) * l1;
    float w2 = EXP2F(m2 - M) * l2;
    float inv = 1.f / (w1 + w2);
    int row = qb * 32 + r;
    size_t o1 = i0 * 2048 + (size_t)r * 64 + hd;
    size_t o2 = (i0 + 1) * 2048 + (size_t)r * 64 + hd;
    size_t ob = ((size_t)b * SEQ + row) * 256 + h * 64 + hd;
    #pragma unroll
    for (int j = 0; j < 32; j++) {
        float v = (w1 * b2f(Op[o1 + j]) + w2 * b2f(Op[o2 + j])) * inv;
        attb[ob + j] = f2b(v);
    }
}

// ---------------- fused pool stage 2 + MLP head (eval BatchNorm) ----------------
__global__ __launch_bounds__(128) void head2_kernel(const float* __restrict__ part,
                                                    const float* __restrict__ h1_w, const float* __restrict__ h1_b,
                                                    const float* __restrict__ g, const float* __restrict__ be,
                                                    const float* __restrict__ mu, const float* __restrict__ var,
                                                    const float* __restrict__ h2_w, const float* __restrict__ h2_b,
                                                    float* __restrict__ out) {
    int b = blockIdx.x, j = threadIdx.x;
    __shared__ float pl[256];
    __shared__ float red[128];
    float s0 = 0.f, s1 = 0.f;
    for (int ch = 0; ch < 32; ch++) {
        s0 += part[((size_t)b * 32 + ch) * 256 + j];
        s1 += part[((size_t)b * 32 + ch) * 256 + j + 128];
    }
    pl[j] = s0 * (1.f / 1024.f);
    pl[j + 128] = s1 * (1.f / 1024.f);
    __syncthreads();
    float s = 0.f;
    for (int d = 0; d < 256; d++) s = fmaf(pl[d], h1_w[j * 256 + d], s);
    s += h1_b[j];
    s = (s - mu[j]) / sqrtf(var[j] + 1e-5f) * g[j] + be[j];
    s = fmaxf(s, 0.f);
    red[j] = s * h2_w[j];
    __syncthreads();
    for (int off = 64; off; off >>= 1) {
        if (j < off) red[j] += red[j + off];
        __syncthreads();
    }
    if (j == 0) out[b] = red[0] + h2_b[0];
}

// ---------------- launch ----------------
extern "C" void kernel_launch(void* const* d_in, const int* in_sizes, int n_in,
                              void* d_out, int out_size, void* d_ws, size_t ws_size,
                              hipStream_t stream) {
    (void)in_sizes; (void)n_in; (void)out_size; (void)ws_size;
    const int*   ids    = (const int*)d_in[0];
    const int*   amask  = (const int*)d_in[1];
    const float* emb_W  = (const float*)d_in[2];
    const float* emb_b  = (const float*)d_in[3];
    const float* wq = (const float*)d_in[4],  *bq = (const float*)d_in[5];
    const float* wk = (const float*)d_in[6],  *bk = (const float*)d_in[7];
    const float* wv = (const float*)d_in[8],  *bv = (const float*)d_in[9];
    const float* fcw = (const float*)d_in[10], *fcb = (const float*)d_in[11];
    const float* f1w = (const float*)d_in[12], *f1b = (const float*)d_in[13];
    const float* f2w = (const float*)d_in[14], *f2b_ = (const float*)d_in[15];
    const float* h1w = (const float*)d_in[16], *h1b = (const float*)d_in[17];
    const float* bng = (const float*)d_in[18], *bnb = (const float*)d_in[19];
    const float* bnm = (const float*)d_in[20], *bnv = (const float*)d_in[21];
    const float* h2w = (const float*)d_in[22], *h2b = (const float*)d_in[23];
    float* out = (float*)d_out;
    float* ws = (float*)d_ws;

    // workspace layout (float units)
    const size_t O_PE   = 0;                        // 262,144
    const size_t O_EMBT = O_PE + 262144;            // 3,840,000 (bf16 30000x256)
    const size_t O_X0B  = O_EMBT + 3840000;         // 2,097,152
    const size_t O_Q    = O_X0B + 2097152;          // 2,097,152
    const size_t O_K    = O_Q + 2097152;            // 2,097,152
    const size_t O_V    = O_K + 2097152;            // 2,097,152
    const size_t O_ATT  = O_V + 2097152;            // 2,097,152
    const size_t O_X1B  = O_ATT + 2097152;          // 2,097,152
    const size_t O_HB   = O_X1B + 2097152;          // 2,097,152
    const size_t O_OP   = O_HB + 2097152;           // 4,194,304 (bf16 4096x32x64)
    const size_t O_ML   = O_OP + 4194304;           // 262,144 (f32 4096x64)
    const size_t O_WQKV = O_ML + 262144;            // 98,304 (768x256 shorts)
    const size_t O_WB3  = O_WQKV + 98304;           // 98,304
    const size_t O_B768 = O_WB3 + 98304;            // 768
    const size_t O_PART = O_B768 + 768;             // 131,072 (16x32x256 f32)
    const size_t O_SPAN = O_PART + 131072;

    float* pe   = ws + O_PE;
    unsigned short* embT = (unsigned short*)(ws + O_EMBT);
    unsigned short* x0b  = (unsigned short*)(ws + O_X0B);
    unsigned short* Qb   = (unsigned short*)(ws + O_Q);
    unsigned short* Kb   = (unsigned short*)(ws + O_K);
    unsigned short* Vt   = (unsigned short*)(ws + O_V);
    unsigned short* attb = (unsigned short*)(ws + O_ATT);
    unsigned short* x1b  = (unsigned short*)(ws + O_X1B);
    unsigned short* hb   = (unsigned short*)(ws + O_HB);
    unsigned short* Op   = (unsigned short*)(ws + O_OP);
    float* ML   = ws + O_ML;
    unsigned short* wqkv = (unsigned short*)(ws + O_WQKV);
    unsigned short* wb3  = (unsigned short*)(ws + O_WB3);
    float* bias768 = ws + O_B768;
    float* part = ws + O_PART;
    int* spans  = (int*)(ws + O_SPAN);

    dim3 tb(32, 8);
    pe2_kernel<<<64, 256, 0, stream>>>(pe);
    span_kernel<<<BATCH, 256, 0, stream>>>(amask, spans);
    cvt_qkv<<<769, 256, 0, stream>>>(wq, wk, wv, bq, bk, bv, wqkv, bias768);
    cvt3<<<768, 256, 0, stream>>>(fcw, f1w, f2w, wb3);
    transpose_b<<<dim3((VOCAB + 31) / 32, 8), tb, 0, stream>>>(emb_W, emb_b, embT);
    embed_kernel<<<MROWS, 256, 0, stream>>>(ids, embT, pe, x0b);

    // fused QKV: N=768, BM=64 -> grid (6,256)
    bgemm<5><<<dim3(6, 256), 256, 0, stream>>>(x0b, wqkv, bias768, nullptr, Qb, Kb, Vt);

    attn_split<<<4096, 64, 0, stream>>>(Qb, Kb, Vt, spans, Op, ML);
    attn_combine<<<2048, 64, 0, stream>>>(Op, ML, attb);

    dim3 gg(2, 256);
    bgemm<2><<<gg, 256, 0, stream>>>(attb, wb3 + 0 * 65536, fcb, x0b, x1b, nullptr, nullptr);
    bgemm<3><<<gg, 256, 0, stream>>>(x1b,  wb3 + 1 * 65536, f1b, nullptr, hb, nullptr, nullptr);
    bgemm<0><<<gg, 256, 0, stream>>>(hb,   wb3 + 2 * 65536, f2b_, nullptr, part, nullptr, nullptr);

    head2_kernel<<<BATCH, 128, 0, stream>>>(part, h1w, h1b, bng, bnb, bnm, bnv, h2w, h2b, out);
}

// Round 6
// 168.314 us; speedup vs baseline: 1.4462x; 1.0325x over previous
//
#include <hip/hip_runtime.h>
#include <math.h>

#define VOCAB 30000
#define DMODEL 256
#define NHEAD 4
#define SEQ 1024
#define BATCH 16
#define MROWS (BATCH*SEQ)   // 16384
#define SL2 0.18033688011112042f            // 0.125 * log2(e)
#define NEG2 (-1.4426950408889634e10f)      // -1e10 * log2(e)

typedef __attribute__((ext_vector_type(8))) short bf16x8;
typedef __attribute__((ext_vector_type(4))) float f32x4;

#if __has_builtin(__builtin_amdgcn_exp2f)
#define EXP2F __builtin_amdgcn_exp2f
#else
#define EXP2F exp2f
#endif

__device__ __forceinline__ unsigned short f2b(float f) {
    unsigned int u = __float_as_uint(f);
    unsigned int r = (u + 0x7FFFu + ((u >> 16) & 1u)) >> 16;
    return (unsigned short)r;
}
__device__ __forceinline__ float b2f(unsigned short s) {
    unsigned int u = ((unsigned int)s) << 16;
    return __uint_as_float(u);
}

// ---------------- transpose W (D x V) -> bf16 embT (V x D), emb_b folded ----------------
__global__ void transpose_b(const float* __restrict__ in, const float* __restrict__ eb,
                            unsigned short* __restrict__ outb) {
    __shared__ float t[32][33];
    int c0 = blockIdx.x * 32, r0 = blockIdx.y * 32;   // c: vocab, r: d
    int tx = threadIdx.x, ty = threadIdx.y;           // 32 x 8
    for (int i = 0; i < 32; i += 8) {
        int r = r0 + ty + i, c = c0 + tx;
        if (c < VOCAB) t[ty + i][tx] = in[(size_t)r * VOCAB + c];
    }
    __syncthreads();
    float ebv = eb[r0 + tx];
    for (int i = 0; i < 32; i += 8) {
        int c = c0 + ty + i, r = r0 + tx;
        if (c < VOCAB) outb[(size_t)c * DMODEL + r] = f2b(t[tx][ty + i] + ebv);
    }
}

// ---------------- merged prologue: pe (64) | span (16) | cvt_qkv (769) | cvt3 (768) ----------------
__global__ void prologue_kernel(const int* __restrict__ mask, int* __restrict__ spans,
                                float* __restrict__ pe,
                                const float* __restrict__ wq, const float* __restrict__ wk,
                                const float* __restrict__ wv, const float* __restrict__ bq,
                                const float* __restrict__ bk, const float* __restrict__ bv,
                                unsigned short* __restrict__ wqkv, float* __restrict__ bias768,
                                const float* __restrict__ fcw, const float* __restrict__ f1w,
                                const float* __restrict__ f2w, unsigned short* __restrict__ wb3) {
    int blk = blockIdx.x;
    int t = threadIdx.x;
    if (blk < 64) {
        __shared__ double down[128];
        if (t < 128) down[t] = exp((double)(2 * t) * (-9.210340371976184 / 256.0));
        __syncthreads();
        int d2 = t & 127, half = t >> 7;
        #pragma unroll
        for (int i = 0; i < 8; i++) {
            int n = blk * 16 + half * 8 + i;
            double ang = (double)n * down[d2];
            pe[n * DMODEL + 2 * d2]     = (float)(sin(ang) * 0.1);
            pe[n * DMODEL + 2 * d2 + 1] = (float)(cos(ang) * 0.1);
        }
    } else if (blk < 80) {
        int b = blk - 64;
        __shared__ int smin, smax;
        if (t == 0) { smin = SEQ; smax = -1; }
        __syncthreads();
        int lmin = SEQ, lmax = -1;
        for (int i = t; i < SEQ; i += 256) {
            if (mask[b * SEQ + i] != 0) { lmin = min(lmin, i); lmax = max(lmax, i); }
        }
        atomicMin(&smin, lmin);
        atomicMax(&smax, lmax);
        __syncthreads();
        if (t == 0) {
            int st, en;
            if (smax < 0) { st = 0; en = SEQ - 1; }
            else          { st = smin; en = smax; }
            spans[b * 2] = st; spans[b * 2 + 1] = en;
        }
    } else if (blk < 849) {
        int cb = blk - 80;
        if (cb < 768) {
            const float* src = (cb < 256) ? wq : (cb < 512) ? wk : wv;
            wqkv[cb * 256 + t] = f2b(src[(cb & 255) * 256 + t]);
        } else {
            for (int j = t; j < 768; j += 256)
                bias768[j] = (j < 256) ? bq[j] : (j < 512) ? bk[j - 256] : bv[j - 512];
        }
    } else {
        int cb = blk - 849;
        const float* src = (cb < 256) ? fcw : (cb < 512) ? f1w : f2w;
        wb3[cb * 256 + t] = f2b(src[(cb & 255) * 256 + t]);
    }
}

// ---------------- embedding gather (coalesced bf16 rows) + pos enc ----------------
__global__ void embed_kernel(const int* __restrict__ ids, const unsigned short* __restrict__ embT,
                             const float* __restrict__ pe, unsigned short* __restrict__ x0b) {
    int bn = blockIdx.x;
    int d = threadIdx.x;
    int id = ids[bn];
    int n = bn & (SEQ - 1);
    float v = b2f(embT[(size_t)id * DMODEL + d]) + pe[n * DMODEL + d];
    x0b[(size_t)bn * DMODEL + d] = f2b(v);
}

// ---------------- bf16 MFMA GEMM: BM=64, BN=128; A(16384x256) @ W^T ----------------
// MODE 0: pooled-partial reduce   MODE 2: bf16 out (+bias+residual bf16)
// MODE 3: bf16 out (+bias+gelu)   MODE 5: fused QKV scatter (Q*SL2; V transposed)
template <int MODE>
__global__ __launch_bounds__(256) void bgemm(const unsigned short* __restrict__ A,
                                             const unsigned short* __restrict__ W,
                                             const float* __restrict__ bias,
                                             const unsigned short* __restrict__ Rres,
                                             void* __restrict__ Cout,
                                             void* __restrict__ Cout2,
                                             void* __restrict__ Cout3) {
    __shared__ unsigned short As[64 * 64];
    __shared__ unsigned short Bs[128 * 64];
    int tid = threadIdx.x;
    int n0 = blockIdx.x * 128, m0 = blockIdx.y * 64;
    int w = tid >> 6, l = tid & 63;
    int wr = (w >> 1) * 32, wc = (w & 1) * 64;
    int lg = l >> 4, ll = l & 15;
    f32x4 acc[2][4] = {};

    for (int k0 = 0; k0 < 256; k0 += 64) {
        __syncthreads();
        #pragma unroll
        for (int i = 0; i < 2; i++) {
            int s = tid + i * 256;
            int row = s >> 3;
            int kb = (s & 7) * 16;
            int swz = kb ^ ((row & 7) << 4);
            float4 av = *(const float4*)((const char*)A + (size_t)(m0 + row) * 512 + k0 * 2 + kb);
            *(float4*)((char*)As + row * 128 + swz) = av;
        }
        #pragma unroll
        for (int i = 0; i < 4; i++) {
            int s = tid + i * 256;
            int row = s >> 3;
            int kb = (s & 7) * 16;
            int swz = kb ^ ((row & 7) << 4);
            float4 bv = *(const float4*)((const char*)W + (size_t)(n0 + row) * 512 + k0 * 2 + kb);
            *(float4*)((char*)Bs + row * 128 + swz) = bv;
        }
        __syncthreads();

        bf16x8 af[2][2], bf[4][2];
        #pragma unroll
        for (int mf = 0; mf < 2; mf++) {
            int row = wr + mf * 16 + ll;
            #pragma unroll
            for (int ks = 0; ks < 2; ks++) {
                int off = (lg * 16 + ks * 64) ^ ((row & 7) << 4);
                af[mf][ks] = *(const bf16x8*)((const char*)As + row * 128 + off);
            }
        }
        #pragma unroll
        for (int nf = 0; nf < 4; nf++) {
            int row = wc + nf * 16 + ll;
            #pragma unroll
            for (int ks = 0; ks < 2; ks++) {
                int off = (lg * 16 + ks * 64) ^ ((row & 7) << 4);
                bf[nf][ks] = *(const bf16x8*)((const char*)Bs + row * 128 + off);
            }
        }
        #pragma unroll
        for (int ks = 0; ks < 2; ks++)
            #pragma unroll
            for (int mf = 0; mf < 2; mf++)
                #pragma unroll
                for (int nf = 0; nf < 4; nf++)
                    acc[mf][nf] = __builtin_amdgcn_mfma_f32_16x16x32_bf16(af[mf][ks], bf[nf][ks], acc[mf][nf], 0, 0, 0);
    }

    float bcol[4];
    #pragma unroll
    for (int nf = 0; nf < 4; nf++) bcol[nf] = bias[n0 + wc + nf * 16 + ll];

    if (MODE == 0) {
        int b = m0 >> 10, ib = (m0 >> 6) & 15, g = wr >> 5;
        #pragma unroll
        for (int nf = 0; nf < 4; nf++) {
            float s = 0.f;
            #pragma unroll
            for (int mf = 0; mf < 2; mf++)
                #pragma unroll
                for (int r = 0; r < 4; r++)
                    s += acc[mf][nf][r];
            s += 8.f * bcol[nf];
            s += __shfl_xor(s, 16);
            s += __shfl_xor(s, 32);
            if (lg == 0) {
                int n = n0 + wc + nf * 16 + ll;
                ((float*)Cout)[((size_t)b * 32 + ib * 2 + g) * 256 + n] = s;
            }
        }
        return;
    }

    #pragma unroll
    for (int mf = 0; mf < 2; mf++) {
        #pragma unroll
        for (int r = 0; r < 4; r++) {
            int m = m0 + wr + mf * 16 + lg * 4 + r;
            #pragma unroll
            for (int nf = 0; nf < 4; nf++) {
                int n = n0 + wc + nf * 16 + ll;
                float v = acc[mf][nf][r] + bcol[nf];
                if (MODE == 2) v += b2f(Rres[(size_t)m * 256 + n]);
                if (MODE == 3) v = 0.5f * v * (1.f + erff(v * 0.70710678118654752f));
                if (MODE == 5) {
                    int which = n >> 8, e = n & 255, hh = e >> 6, dk = e & 63;
                    int bb = m >> 10, ns = m & 1023;
                    if (which == 0)
                        ((unsigned short*)Cout)[((((size_t)bb * 4 + hh) * 1024) + ns) * 64 + dk] = f2b(v * SL2);
                    else if (which == 1)
                        ((unsigned short*)Cout2)[((((size_t)bb * 4 + hh) * 1024) + ns) * 64 + dk] = f2b(v);
                    else
                        ((unsigned short*)Cout3)[((((size_t)bb * 4 + hh) * 64) + dk) * 1024 + ns] = f2b(v);
                } else {
                    ((unsigned short*)Cout)[(size_t)m * 256 + n] = f2b(v);
                }
            }
        }
    }
}

// ---------------- split-KV flash attention, NO max tracking, l via MFMA ones-column ----------------
// Scores pre-scaled to log2 domain (Q * SL2). Masked col: +NEG2 -> exp2 -> 0 exactly.
// Masked row: s=0 for ALL cols -> p=1 uniform (matches ref fp32 -1e10-swamp semantics).
__global__ __launch_bounds__(64) void attn_split(const unsigned short* __restrict__ Qb,
                                                 const unsigned short* __restrict__ Kb,
                                                 const unsigned short* __restrict__ Vt,
                                                 const int* __restrict__ spans,
                                                 unsigned short* __restrict__ Op,
                                                 float* __restrict__ Lp) {
    __shared__ __align__(16) unsigned short Ps[32 * 72];
    int id = blockIdx.x;
    int xcd = id & 7, j = id >> 3;
    int bh = xcd * 8 + (j >> 6);
    int rem = j & 63;
    int qb = rem >> 1, sp = rem & 1;
    int q0 = qb * 32;
    int b = bh >> 2;
    int l = threadIdx.x;
    int lg = l >> 4, ll = l & 15;
    const char* Kp = (const char*)(Kb + (size_t)bh * SEQ * 64);
    const char* Vp = (const char*)(Vt + (size_t)bh * 64 * SEQ);
    const unsigned short* Qp = Qb + (size_t)bh * SEQ * 64;
    int start = spans[b * 2], end = spans[b * 2 + 1];

    bf16x8 qf[2][2];
    #pragma unroll
    for (int mf = 0; mf < 2; mf++)
        #pragma unroll
        for (int ks = 0; ks < 2; ks++)
            qf[mf][ks] = *(const bf16x8*)(Qp + (size_t)(q0 + mf * 16 + ll) * 64 + lg * 8 + ks * 32);

    bf16x8 ones;
    #pragma unroll
    for (int i = 0; i < 8; i++) ones[i] = (short)0x3F80;   // bf16 1.0

    f32x4 o[2][4] = {};
    f32x4 accl[2] = {};
    bool rowok[2][4];
    #pragma unroll
    for (int mf = 0; mf < 2; mf++)
        #pragma unroll
        for (int r2 = 0; r2 < 4; r2++) {
            int rr = q0 + mf * 16 + lg * 4 + r2;
            rowok[mf][r2] = (rr >= start) && (rr < end);
        }

    const char* kbase = Kp + (size_t)ll * 128 + lg * 16;
    const char* vbase = Vp + (size_t)ll * 2048 + lg * 16;

    for (int ct = 0; ct < 8; ct++) {
        int kv0 = sp * 512 + ct * 64;

        bf16x8 kf[4][2];
        #pragma unroll
        for (int nf = 0; nf < 4; nf++)
            #pragma unroll
            for (int ks = 0; ks < 2; ks++)
                kf[nf][ks] = *(const bf16x8*)(kbase + (size_t)kv0 * 128 + nf * 2048 + ks * 64);

        f32x4 s[2][4] = {};
        #pragma unroll
        for (int ks = 0; ks < 2; ks++)
            #pragma unroll
            for (int mf = 0; mf < 2; mf++)
                #pragma unroll
                for (int nf = 0; nf < 4; nf++)
                    s[mf][nf] = __builtin_amdgcn_mfma_f32_16x16x32_bf16(qf[mf][ks], kf[nf][ks], s[mf][nf], 0, 0, 0);

        bool colok[4];
        #pragma unroll
        for (int nf = 0; nf < 4; nf++) {
            int cc = kv0 + nf * 16 + ll;
            colok[nf] = (cc >= start) && (cc < end);
        }
        #pragma unroll
        for (int mf = 0; mf < 2; mf++)
            #pragma unroll
            for (int nf = 0; nf < 4; nf++)
                #pragma unroll
                for (int r2 = 0; r2 < 4; r2++) {
                    float sv = s[mf][nf][r2];
                    sv = colok[nf] ? sv : sv + NEG2;
                    sv = rowok[mf][r2] ? sv : 0.f;
                    s[mf][nf][r2] = EXP2F(sv);
                }

        // P -> per-wave LDS (bf16) for A-fragment relayout (single wave, no barrier)
        #pragma unroll
        for (int mf = 0; mf < 2; mf++)
            #pragma unroll
            for (int nf = 0; nf < 4; nf++)
                #pragma unroll
                for (int r2 = 0; r2 < 4; r2++)
                    Ps[(mf * 16 + lg * 4 + r2) * 72 + nf * 16 + ll] = f2b(s[mf][nf][r2]);

        bf16x8 pa[2][2], vf[4][2];
        #pragma unroll
        for (int rf = 0; rf < 2; rf++) {
            int row = rf * 16 + ll;
            #pragma unroll
            for (int ks = 0; ks < 2; ks++)
                pa[rf][ks] = *(const bf16x8*)(&Ps[row * 72 + lg * 8 + ks * 32]);
        }
        #pragma unroll
        for (int cf = 0; cf < 4; cf++)
            #pragma unroll
            for (int ks = 0; ks < 2; ks++)
                vf[cf][ks] = *(const bf16x8*)(vbase + (size_t)cf * 32768 + kv0 * 2 + ks * 64);
        #pragma unroll
        for (int ks = 0; ks < 2; ks++)
            #pragma unroll
            for (int rf = 0; rf < 2; rf++) {
                #pragma unroll
                for (int cf = 0; cf < 4; cf++)
                    o[rf][cf] = __builtin_amdgcn_mfma_f32_16x16x32_bf16(pa[rf][ks], vf[cf][ks], o[rf][cf], 0, 0, 0);
                accl[rf] = __builtin_amdgcn_mfma_f32_16x16x32_bf16(pa[rf][ks], ones, accl[rf], 0, 0, 0);
            }
    }

    // write unnormalized partial o (bf16) + l (f32)
    size_t idx = ((size_t)(bh * 32 + qb)) * 2 + sp;
    #pragma unroll
    for (int rf = 0; rf < 2; rf++)
        #pragma unroll
        for (int r2 = 0; r2 < 4; r2++) {
            int rl = rf * 16 + lg * 4 + r2;
            #pragma unroll
            for (int cf = 0; cf < 4; cf++)
                Op[idx * 2048 + rl * 64 + cf * 16 + ll] = f2b(o[rf][cf][r2]);
            if (ll == 0)
                Lp[idx * 32 + rl] = accl[rf][r2];
        }
}

// ---------------- combine 2 splits: (o1+o2)/(l1+l2) -> attb (B,N,256) bf16 ----------------
__global__ __launch_bounds__(64) void attn_combine(const unsigned short* __restrict__ Op,
                                                   const float* __restrict__ Lp,
                                                   unsigned short* __restrict__ attb) {
    int cid = blockIdx.x;              // bh*32 + qb
    int bh = cid >> 5, qb = cid & 31;
    int b = bh >> 2, h = bh & 3;
    int t = threadIdx.x;
    int r = t >> 1, half = (t & 1) * 32;
    size_t i0 = (size_t)cid * 2;
    float l1 = Lp[i0 * 32 + r];
    float l2 = Lp[(i0 + 1) * 32 + r];
    float inv = 1.f / (l1 + l2);
    const unsigned short* p1 = Op + i0 * 2048 + (size_t)r * 64 + half;
    const unsigned short* p2 = Op + (i0 + 1) * 2048 + (size_t)r * 64 + half;
    unsigned short* po = attb + ((size_t)b * SEQ + qb * 32 + r) * 256 + h * 64 + half;
    #pragma unroll
    for (int c = 0; c < 4; c++) {
        bf16x8 a = *(const bf16x8*)(p1 + c * 8);
        bf16x8 bb = *(const bf16x8*)(p2 + c * 8);
        bf16x8 res;
        #pragma unroll
        for (int jj = 0; jj < 8; jj++)
            res[jj] = (short)f2b((b2f((unsigned short)a[jj]) + b2f((unsigned short)bb[jj])) * inv);
        *(bf16x8*)(po + c * 8) = res;
    }
}

// ---------------- fused pool stage 2 + MLP head (eval BatchNorm) ----------------
__global__ __launch_bounds__(128) void head2_kernel(const float* __restrict__ part,
                                                    const float* __restrict__ h1_w, const float* __restrict__ h1_b,
                                                    const float* __restrict__ g, const float* __restrict__ be,
                                                    const float* __restrict__ mu, const float* __restrict__ var,
                                                    const float* __restrict__ h2_w, const float* __restrict__ h2_b,
                                                    float* __restrict__ out) {
    int b = blockIdx.x, j = threadIdx.x;
    __shared__ float pl[256];
    __shared__ float red[128];
    float s0 = 0.f, s1 = 0.f;
    for (int ch = 0; ch < 32; ch++) {
        s0 += part[((size_t)b * 32 + ch) * 256 + j];
        s1 += part[((size_t)b * 32 + ch) * 256 + j + 128];
    }
    pl[j] = s0 * (1.f / 1024.f);
    pl[j + 128] = s1 * (1.f / 1024.f);
    __syncthreads();
    float s = 0.f;
    for (int d = 0; d < 256; d++) s = fmaf(pl[d], h1_w[j * 256 + d], s);
    s += h1_b[j];
    s = (s - mu[j]) / sqrtf(var[j] + 1e-5f) * g[j] + be[j];
    s = fmaxf(s, 0.f);
    red[j] = s * h2_w[j];
    __syncthreads();
    for (int off = 64; off; off >>= 1) {
        if (j < off) red[j] += red[j + off];
        __syncthreads();
    }
    if (j == 0) out[b] = red[0] + h2_b[0];
}

// ---------------- launch ----------------
extern "C" void kernel_launch(void* const* d_in, const int* in_sizes, int n_in,
                              void* d_out, int out_size, void* d_ws, size_t ws_size,
                              hipStream_t stream) {
    (void)in_sizes; (void)n_in; (void)out_size; (void)ws_size;
    const int*   ids    = (const int*)d_in[0];
    const int*   amask  = (const int*)d_in[1];
    const float* emb_W  = (const float*)d_in[2];
    const float* emb_b  = (const float*)d_in[3];
    const float* wq = (const float*)d_in[4],  *bq = (const float*)d_in[5];
    const float* wk = (const float*)d_in[6],  *bk = (const float*)d_in[7];
    const float* wv = (const float*)d_in[8],  *bv = (const float*)d_in[9];
    const float* fcw = (const float*)d_in[10], *fcb = (const float*)d_in[11];
    const float* f1w = (const float*)d_in[12], *f1b = (const float*)d_in[13];
    const float* f2w = (const float*)d_in[14], *f2b_ = (const float*)d_in[15];
    const float* h1w = (const float*)d_in[16], *h1b = (const float*)d_in[17];
    const float* bng = (const float*)d_in[18], *bnb = (const float*)d_in[19];
    const float* bnm = (const float*)d_in[20], *bnv = (const float*)d_in[21];
    const float* h2w = (const float*)d_in[22], *h2b = (const float*)d_in[23];
    float* out = (float*)d_out;
    float* ws = (float*)d_ws;

    // workspace layout (float units)
    const size_t O_PE   = 0;                        // 262,144
    const size_t O_EMBT = O_PE + 262144;            // 3,840,000 (bf16 30000x256)
    const size_t O_X0B  = O_EMBT + 3840000;         // 2,097,152
    const size_t O_Q    = O_X0B + 2097152;          // 2,097,152
    const size_t O_K    = O_Q + 2097152;            // 2,097,152
    const size_t O_V    = O_K + 2097152;            // 2,097,152
    const size_t O_ATT  = O_V + 2097152;            // 2,097,152
    const size_t O_X1B  = O_ATT + 2097152;          // 2,097,152
    const size_t O_HB   = O_X1B + 2097152;          // 2,097,152
    const size_t O_OP   = O_HB + 2097152;           // 4,194,304 (bf16 4096x2048)
    const size_t O_ML   = O_OP + 4194304;           // 131,072 (f32 4096x32)
    const size_t O_WQKV = O_ML + 262144;            // 98,304 (768x256 shorts)
    const size_t O_WB3  = O_WQKV + 98304;           // 98,304
    const size_t O_B768 = O_WB3 + 98304;            // 768
    const size_t O_PART = O_B768 + 768;             // 131,072 (16x32x256 f32)
    const size_t O_SPAN = O_PART + 131072;

    float* pe   = ws + O_PE;
    unsigned short* embT = (unsigned short*)(ws + O_EMBT);
    unsigned short* x0b  = (unsigned short*)(ws + O_X0B);
    unsigned short* Qb   = (unsigned short*)(ws + O_Q);
    unsigned short* Kb   = (unsigned short*)(ws + O_K);
    unsigned short* Vt   = (unsigned short*)(ws + O_V);
    unsigned short* attb = (unsigned short*)(ws + O_ATT);
    unsigned short* x1b  = (unsigned short*)(ws + O_X1B);
    unsigned short* hb   = (unsigned short*)(ws + O_HB);
    unsigned short* Op   = (unsigned short*)(ws + O_OP);
    float* Lp   = ws + O_ML;
    unsigned short* wqkv = (unsigned short*)(ws + O_WQKV);
    unsigned short* wb3  = (unsigned short*)(ws + O_WB3);
    float* bias768 = ws + O_B768;
    float* part = ws + O_PART;
    int* spans  = (int*)(ws + O_SPAN);

    dim3 tb(32, 8);
    prologue_kernel<<<1617, 256, 0, stream>>>(amask, spans, pe,
                                              wq, wk, wv, bq, bk, bv, wqkv, bias768,
                                              fcw, f1w, f2w, wb3);
    transpose_b<<<dim3((VOCAB + 31) / 32, 8), tb, 0, stream>>>(emb_W, emb_b, embT);
    embed_kernel<<<MROWS, 256, 0, stream>>>(ids, embT, pe, x0b);

    // fused QKV: N=768, BM=64 -> grid (6,256)
    bgemm<5><<<dim3(6, 256), 256, 0, stream>>>(x0b, wqkv, bias768, nullptr, Qb, Kb, Vt);

    attn_split<<<4096, 64, 0, stream>>>(Qb, Kb, Vt, spans, Op, Lp);
    attn_combine<<<2048, 64, 0, stream>>>(Op, Lp, attb);

    dim3 gg(2, 256);
    bgemm<2><<<gg, 256, 0, stream>>>(attb, wb3 + 0 * 65536, fcb, x0b, x1b, nullptr, nullptr);
    bgemm<3><<<gg, 256, 0, stream>>>(x1b,  wb3 + 1 * 65536, f1b, nullptr, hb, nullptr, nullptr);
    bgemm<0><<<gg, 256, 0, stream>>>(hb,   wb3 + 2 * 65536, f2b_, nullptr, part, nullptr, nullptr);

    head2_kernel<<<BATCH, 128, 0, stream>>>(part, h1w, h1b, bng, bnb, bnm, bnv, h2w, h2b, out);
}

// Round 7
// 161.156 us; speedup vs baseline: 1.5104x; 1.0444x over previous
//
#include <hip/hip_runtime.h>
#include <math.h>

#define VOCAB 30000
#define DMODEL 256
#define NHEAD 4
#define SEQ 1024
#define BATCH 16
#define MROWS (BATCH*SEQ)   // 16384
#define SL2 0.18033688011112042f            // 0.125 * log2(e)
#define NEG2 (-1.4426950408889634e10f)      // -1e10 * log2(e)

typedef __attribute__((ext_vector_type(8))) short bf16x8;
typedef __attribute__((ext_vector_type(4))) float f32x4;

#if __has_builtin(__builtin_amdgcn_exp2f)
#define EXP2F __builtin_amdgcn_exp2f
#else
#define EXP2F exp2f
#endif

__device__ __forceinline__ unsigned short f2b(float f) {
    unsigned int u = __float_as_uint(f);
    unsigned int r = (u + 0x7FFFu + ((u >> 16) & 1u)) >> 16;
    return (unsigned short)r;
}
__device__ __forceinline__ unsigned short f2b_trunc(float f) {
    return (unsigned short)(__float_as_uint(f) >> 16);
}
__device__ __forceinline__ float b2f(unsigned short s) {
    unsigned int u = ((unsigned int)s) << 16;
    return __uint_as_float(u);
}

// ---------------- transpose W (D x V) -> bf16 embT (V x D), emb_b folded ----------------
__global__ void transpose_b(const float* __restrict__ in, const float* __restrict__ eb,
                            unsigned short* __restrict__ outb) {
    __shared__ float t[32][33];
    int c0 = blockIdx.x * 32, r0 = blockIdx.y * 32;   // c: vocab, r: d
    int tx = threadIdx.x, ty = threadIdx.y;           // 32 x 8
    for (int i = 0; i < 32; i += 8) {
        int r = r0 + ty + i, c = c0 + tx;
        if (c < VOCAB) t[ty + i][tx] = in[(size_t)r * VOCAB + c];
    }
    __syncthreads();
    float ebv = eb[r0 + tx];
    for (int i = 0; i < 32; i += 8) {
        int c = c0 + ty + i, r = r0 + tx;
        if (c < VOCAB) outb[(size_t)c * DMODEL + r] = f2b(t[tx][ty + i] + ebv);
    }
}

// ---------------- merged prologue: pe (64) | span (16) | cvt_qkv (769) | cvt3 (768) ----------------
__global__ void prologue_kernel(const int* __restrict__ mask, int* __restrict__ spans,
                                float* __restrict__ pe,
                                const float* __restrict__ wq, const float* __restrict__ wk,
                                const float* __restrict__ wv, const float* __restrict__ bq,
                                const float* __restrict__ bk, const float* __restrict__ bv,
                                unsigned short* __restrict__ wqkv, float* __restrict__ bias768,
                                const float* __restrict__ fcw, const float* __restrict__ f1w,
                                const float* __restrict__ f2w, unsigned short* __restrict__ wb3) {
    int blk = blockIdx.x;
    int t = threadIdx.x;
    if (blk < 64) {
        __shared__ double down[128];
        if (t < 128) down[t] = exp((double)(2 * t) * (-9.210340371976184 / 256.0));
        __syncthreads();
        int d2 = t & 127, half = t >> 7;
        #pragma unroll
        for (int i = 0; i < 8; i++) {
            int n = blk * 16 + half * 8 + i;
            double ang = (double)n * down[d2];
            pe[n * DMODEL + 2 * d2]     = (float)(sin(ang) * 0.1);
            pe[n * DMODEL + 2 * d2 + 1] = (float)(cos(ang) * 0.1);
        }
    } else if (blk < 80) {
        int b = blk - 64;
        __shared__ int smin, smax;
        if (t == 0) { smin = SEQ; smax = -1; }
        __syncthreads();
        int lmin = SEQ, lmax = -1;
        for (int i = t; i < SEQ; i += 256) {
            if (mask[b * SEQ + i] != 0) { lmin = min(lmin, i); lmax = max(lmax, i); }
        }
        atomicMin(&smin, lmin);
        atomicMax(&smax, lmax);
        __syncthreads();
        if (t == 0) {
            int st, en;
            if (smax < 0) { st = 0; en = SEQ - 1; }
            else          { st = smin; en = smax; }
            spans[b * 2] = st; spans[b * 2 + 1] = en;
        }
    } else if (blk < 849) {
        int cb = blk - 80;
        if (cb < 768) {
            const float* src = (cb < 256) ? wq : (cb < 512) ? wk : wv;
            wqkv[cb * 256 + t] = f2b(src[(cb & 255) * 256 + t]);
        } else {
            for (int j = t; j < 768; j += 256)
                bias768[j] = (j < 256) ? bq[j] : (j < 512) ? bk[j - 256] : bv[j - 512];
        }
    } else {
        int cb = blk - 849;
        const float* src = (cb < 256) ? fcw : (cb < 512) ? f1w : f2w;
        wb3[cb * 256 + t] = f2b(src[(cb & 255) * 256 + t]);
    }
}

// ---------------- embedding gather (coalesced bf16 rows) + pos enc ----------------
__global__ void embed_kernel(const int* __restrict__ ids, const unsigned short* __restrict__ embT,
                             const float* __restrict__ pe, unsigned short* __restrict__ x0b) {
    int bn = blockIdx.x;
    int d = threadIdx.x;
    int id = ids[bn];
    int n = bn & (SEQ - 1);
    float v = b2f(embT[(size_t)id * DMODEL + d]) + pe[n * DMODEL + d];
    x0b[(size_t)bn * DMODEL + d] = f2b(v);
}

// ---------------- bf16 MFMA GEMM: BM=64, BN=128; A(16384x256) @ W^T ----------------
// MODE 0: pooled-partial reduce   MODE 2: bf16 out (+bias+residual bf16)
// MODE 3: bf16 out (+bias+gelu)   MODE 5: fused QKV scatter (Q*SL2; V transposed)
template <int MODE>
__global__ __launch_bounds__(256) void bgemm(const unsigned short* __restrict__ A,
                                             const unsigned short* __restrict__ W,
                                             const float* __restrict__ bias,
                                             const unsigned short* __restrict__ Rres,
                                             void* __restrict__ Cout,
                                             void* __restrict__ Cout2,
                                             void* __restrict__ Cout3) {
    __shared__ unsigned short As[64 * 64];
    __shared__ unsigned short Bs[128 * 64];
    int tid = threadIdx.x;
    int n0 = blockIdx.x * 128, m0 = blockIdx.y * 64;
    int w = tid >> 6, l = tid & 63;
    int wr = (w >> 1) * 32, wc = (w & 1) * 64;
    int lg = l >> 4, ll = l & 15;
    f32x4 acc[2][4] = {};

    for (int k0 = 0; k0 < 256; k0 += 64) {
        __syncthreads();
        #pragma unroll
        for (int i = 0; i < 2; i++) {
            int s = tid + i * 256;
            int row = s >> 3;
            int kb = (s & 7) * 16;
            int swz = kb ^ ((row & 7) << 4);
            float4 av = *(const float4*)((const char*)A + (size_t)(m0 + row) * 512 + k0 * 2 + kb);
            *(float4*)((char*)As + row * 128 + swz) = av;
        }
        #pragma unroll
        for (int i = 0; i < 4; i++) {
            int s = tid + i * 256;
            int row = s >> 3;
            int kb = (s & 7) * 16;
            int swz = kb ^ ((row & 7) << 4);
            float4 bv = *(const float4*)((const char*)W + (size_t)(n0 + row) * 512 + k0 * 2 + kb);
            *(float4*)((char*)Bs + row * 128 + swz) = bv;
        }
        __syncthreads();

        bf16x8 af[2][2], bf[4][2];
        #pragma unroll
        for (int mf = 0; mf < 2; mf++) {
            int row = wr + mf * 16 + ll;
            #pragma unroll
            for (int ks = 0; ks < 2; ks++) {
                int off = (lg * 16 + ks * 64) ^ ((row & 7) << 4);
                af[mf][ks] = *(const bf16x8*)((const char*)As + row * 128 + off);
            }
        }
        #pragma unroll
        for (int nf = 0; nf < 4; nf++) {
            int row = wc + nf * 16 + ll;
            #pragma unroll
            for (int ks = 0; ks < 2; ks++) {
                int off = (lg * 16 + ks * 64) ^ ((row & 7) << 4);
                bf[nf][ks] = *(const bf16x8*)((const char*)Bs + row * 128 + off);
            }
        }
        #pragma unroll
        for (int ks = 0; ks < 2; ks++)
            #pragma unroll
            for (int mf = 0; mf < 2; mf++)
                #pragma unroll
                for (int nf = 0; nf < 4; nf++)
                    acc[mf][nf] = __builtin_amdgcn_mfma_f32_16x16x32_bf16(af[mf][ks], bf[nf][ks], acc[mf][nf], 0, 0, 0);
    }

    float bcol[4];
    #pragma unroll
    for (int nf = 0; nf < 4; nf++) bcol[nf] = bias[n0 + wc + nf * 16 + ll];

    if (MODE == 0) {
        int b = m0 >> 10, ib = (m0 >> 6) & 15, g = wr >> 5;
        #pragma unroll
        for (int nf = 0; nf < 4; nf++) {
            float s = 0.f;
            #pragma unroll
            for (int mf = 0; mf < 2; mf++)
                #pragma unroll
                for (int r = 0; r < 4; r++)
                    s += acc[mf][nf][r];
            s += 8.f * bcol[nf];
            s += __shfl_xor(s, 16);
            s += __shfl_xor(s, 32);
            if (lg == 0) {
                int n = n0 + wc + nf * 16 + ll;
                ((float*)Cout)[((size_t)b * 32 + ib * 2 + g) * 256 + n] = s;
            }
        }
        return;
    }

    #pragma unroll
    for (int mf = 0; mf < 2; mf++) {
        #pragma unroll
        for (int r = 0; r < 4; r++) {
            int m = m0 + wr + mf * 16 + lg * 4 + r;
            #pragma unroll
            for (int nf = 0; nf < 4; nf++) {
                int n = n0 + wc + nf * 16 + ll;
                float v = acc[mf][nf][r] + bcol[nf];
                if (MODE == 2) v += b2f(Rres[(size_t)m * 256 + n]);
                if (MODE == 3) v = 0.5f * v * (1.f + erff(v * 0.70710678118654752f));
                if (MODE == 5) {
                    int which = n >> 8, e = n & 255, hh = e >> 6, dk = e & 63;
                    int bb = m >> 10, ns = m & 1023;
                    if (which == 0)
                        ((unsigned short*)Cout)[((((size_t)bb * 4 + hh) * 1024) + ns) * 64 + dk] = f2b(v * SL2);
                    else if (which == 1)
                        ((unsigned short*)Cout2)[((((size_t)bb * 4 + hh) * 1024) + ns) * 64 + dk] = f2b(v);
                    else
                        ((unsigned short*)Cout3)[((((size_t)bb * 4 + hh) * 64) + dk) * 1024 + ns] = f2b(v);
                } else {
                    ((unsigned short*)Cout)[(size_t)m * 256 + n] = f2b(v);
                }
            }
        }
    }
}

// ---------------- split-KV flash attention, 4 independent waves / 256-thread block ----------------
// No max tracking (log2-domain scores, fixed m=0); l via MFMA ones-column.
// Masked col: +NEG2 -> exp2 -> 0.  Masked row: s=0 all cols -> uniform (ref semantics).
__global__ __launch_bounds__(256) void attn_split(const unsigned short* __restrict__ Qb,
                                                  const unsigned short* __restrict__ Kb,
                                                  const unsigned short* __restrict__ Vt,
                                                  const int* __restrict__ spans,
                                                  unsigned short* __restrict__ Op,
                                                  float* __restrict__ Lp) {
    __shared__ __align__(16) unsigned short Ps[4][32 * 72];   // per-wave slice, no barriers
    int tid = threadIdx.x;
    int w = tid >> 6, l = tid & 63;
    int id = blockIdx.x;               // 0..1023
    int c = id & 7, j = id >> 3;       // c: XCD class; j 0..127
    int bh = c * 8 + (j >> 4);         // all 16 blocks of a bh share one XCD class
    int rem = j & 15;
    int qb = rem * 2 + (w >> 1);
    int sp = w & 1;
    int q0 = qb * 32;
    int b = bh >> 2;
    int lg = l >> 4, ll = l & 15;
    const char* Kp = (const char*)(Kb + (size_t)bh * SEQ * 64);
    const char* Vp = (const char*)(Vt + (size_t)bh * 64 * SEQ);
    const unsigned short* Qp = Qb + (size_t)bh * SEQ * 64;
    int start = spans[b * 2], end = spans[b * 2 + 1];

    bf16x8 qf[2][2];
    #pragma unroll
    for (int mf = 0; mf < 2; mf++)
        #pragma unroll
        for (int ks = 0; ks < 2; ks++)
            qf[mf][ks] = *(const bf16x8*)(Qp + (size_t)(q0 + mf * 16 + ll) * 64 + lg * 8 + ks * 32);

    bf16x8 ones;
    #pragma unroll
    for (int i = 0; i < 8; i++) ones[i] = (short)0x3F80;   // bf16 1.0

    f32x4 o[2][4] = {};
    f32x4 accl[2] = {};
    bool rowok[2][4];
    #pragma unroll
    for (int mf = 0; mf < 2; mf++)
        #pragma unroll
        for (int r2 = 0; r2 < 4; r2++) {
            int rr = q0 + mf * 16 + lg * 4 + r2;
            rowok[mf][r2] = (rr >= start) && (rr < end);
        }

    const char* kbase = Kp + (size_t)ll * 128 + lg * 16;
    const char* vbase = Vp + (size_t)ll * 2048 + lg * 16;

    for (int ct = 0; ct < 8; ct++) {
        int kv0 = sp * 512 + ct * 64;

        // K fragments + early V prefetch (independent of softmax chain)
        bf16x8 kf[4][2], vf[4][2];
        #pragma unroll
        for (int nf = 0; nf < 4; nf++)
            #pragma unroll
            for (int ks = 0; ks < 2; ks++)
                kf[nf][ks] = *(const bf16x8*)(kbase + (size_t)kv0 * 128 + nf * 2048 + ks * 64);
        #pragma unroll
        for (int cf = 0; cf < 4; cf++)
            #pragma unroll
            for (int ks = 0; ks < 2; ks++)
                vf[cf][ks] = *(const bf16x8*)(vbase + (size_t)cf * 32768 + kv0 * 2 + ks * 64);

        f32x4 s[2][4] = {};
        #pragma unroll
        for (int ks = 0; ks < 2; ks++)
            #pragma unroll
            for (int mf = 0; mf < 2; mf++)
                #pragma unroll
                for (int nf = 0; nf < 4; nf++)
                    s[mf][nf] = __builtin_amdgcn_mfma_f32_16x16x32_bf16(qf[mf][ks], kf[nf][ks], s[mf][nf], 0, 0, 0);

        bool colok[4];
        #pragma unroll
        for (int nf = 0; nf < 4; nf++) {
            int cc = kv0 + nf * 16 + ll;
            colok[nf] = (cc >= start) && (cc < end);
        }
        #pragma unroll
        for (int mf = 0; mf < 2; mf++)
            #pragma unroll
            for (int nf = 0; nf < 4; nf++)
                #pragma unroll
                for (int r2 = 0; r2 < 4; r2++) {
                    float sv = s[mf][nf][r2];
                    sv = colok[nf] ? sv : sv + NEG2;
                    sv = rowok[mf][r2] ? sv : 0.f;
                    s[mf][nf][r2] = EXP2F(sv);
                }

        // P -> per-wave LDS slice (bf16 trunc) for A-fragment relayout
        #pragma unroll
        for (int mf = 0; mf < 2; mf++)
            #pragma unroll
            for (int nf = 0; nf < 4; nf++)
                #pragma unroll
                for (int r2 = 0; r2 < 4; r2++)
                    Ps[w][(mf * 16 + lg * 4 + r2) * 72 + nf * 16 + ll] = f2b_trunc(s[mf][nf][r2]);

        bf16x8 pa[2][2];
        #pragma unroll
        for (int rf = 0; rf < 2; rf++) {
            int row = rf * 16 + ll;
            #pragma unroll
            for (int ks = 0; ks < 2; ks++)
                pa[rf][ks] = *(const bf16x8*)(&Ps[w][row * 72 + lg * 8 + ks * 32]);
        }
        #pragma unroll
        for (int ks = 0; ks < 2; ks++)
            #pragma unroll
            for (int rf = 0; rf < 2; rf++) {
                #pragma unroll
                for (int cf = 0; cf < 4; cf++)
                    o[rf][cf] = __builtin_amdgcn_mfma_f32_16x16x32_bf16(pa[rf][ks], vf[cf][ks], o[rf][cf], 0, 0, 0);
                accl[rf] = __builtin_amdgcn_mfma_f32_16x16x32_bf16(pa[rf][ks], ones, accl[rf], 0, 0, 0);
            }
    }

    // write unnormalized partial o (bf16) + l (f32)
    size_t idx = ((size_t)(bh * 32 + qb)) * 2 + sp;
    #pragma unroll
    for (int rf = 0; rf < 2; rf++)
        #pragma unroll
        for (int r2 = 0; r2 < 4; r2++) {
            int rl = rf * 16 + lg * 4 + r2;
            #pragma unroll
            for (int cf = 0; cf < 4; cf++)
                Op[idx * 2048 + rl * 64 + cf * 16 + ll] = f2b(o[rf][cf][r2]);
            if (ll == 0)
                Lp[idx * 32 + rl] = accl[rf][r2];
        }
}

// ---------------- combine 2 splits: (o1+o2)/(l1+l2) -> attb (B,N,256) bf16 ----------------
__global__ __launch_bounds__(64) void attn_combine(const unsigned short* __restrict__ Op,
                                                   const float* __restrict__ Lp,
                                                   unsigned short* __restrict__ attb) {
    int cid = blockIdx.x;              // bh*32 + qb
    int bh = cid >> 5, qb = cid & 31;
    int b = bh >> 2, h = bh & 3;
    int t = threadIdx.x;
    int r = t >> 1, half = (t & 1) * 32;
    size_t i0 = (size_t)cid * 2;
    float l1 = Lp[i0 * 32 + r];
    float l2 = Lp[(i0 + 1) * 32 + r];
    float inv = 1.f / (l1 + l2);
    const unsigned short* p1 = Op + i0 * 2048 + (size_t)r * 64 + half;
    const unsigned short* p2 = Op + (i0 + 1) * 2048 + (size_t)r * 64 + half;
    unsigned short* po = attb + ((size_t)b * SEQ + qb * 32 + r) * 256 + h * 64 + half;
    #pragma unroll
    for (int c = 0; c < 4; c++) {
        bf16x8 a = *(const bf16x8*)(p1 + c * 8);
        bf16x8 bb = *(const bf16x8*)(p2 + c * 8);
        bf16x8 res;
        #pragma unroll
        for (int jj = 0; jj < 8; jj++)
            res[jj] = (short)f2b((b2f((unsigned short)a[jj]) + b2f((unsigned short)bb[jj])) * inv);
        *(bf16x8*)(po + c * 8) = res;
    }
}

// ---------------- fused pool stage 2 + MLP head (eval BatchNorm) ----------------
__global__ __launch_bounds__(128) void head2_kernel(const float* __restrict__ part,
                                                    const float* __restrict__ h1_w, const float* __restrict__ h1_b,
                                                    const float* __restrict__ g, const float* __restrict__ be,
                                                    const float* __restrict__ mu, const float* __restrict__ var,
                                                    const float* __restrict__ h2_w, const float* __restrict__ h2_b,
                                                    float* __restrict__ out) {
    int b = blockIdx.x, j = threadIdx.x;
    __shared__ float pl[256];
    __shared__ float red[128];
    float s0 = 0.f, s1 = 0.f;
    for (int ch = 0; ch < 32; ch++) {
        s0 += part[((size_t)b * 32 + ch) * 256 + j];
        s1 += part[((size_t)b * 32 + ch) * 256 + j + 128];
    }
    pl[j] = s0 * (1.f / 1024.f);
    pl[j + 128] = s1 * (1.f / 1024.f);
    __syncthreads();
    float s = 0.f;
    for (int d = 0; d < 256; d++) s = fmaf(pl[d], h1_w[j * 256 + d], s);
    s += h1_b[j];
    s = (s - mu[j]) / sqrtf(var[j] + 1e-5f) * g[j] + be[j];
    s = fmaxf(s, 0.f);
    red[j] = s * h2_w[j];
    __syncthreads();
    for (int off = 64; off; off >>= 1) {
        if (j < off) red[j] += red[j + off];
        __syncthreads();
    }
    if (j == 0) out[b] = red[0] + h2_b[0];
}

// ---------------- launch ----------------
extern "C" void kernel_launch(void* const* d_in, const int* in_sizes, int n_in,
                              void* d_out, int out_size, void* d_ws, size_t ws_size,
                              hipStream_t stream) {
    (void)in_sizes; (void)n_in; (void)out_size; (void)ws_size;
    const int*   ids    = (const int*)d_in[0];
    const int*   amask  = (const int*)d_in[1];
    const float* emb_W  = (const float*)d_in[2];
    const float* emb_b  = (const float*)d_in[3];
    const float* wq = (const float*)d_in[4],  *bq = (const float*)d_in[5];
    const float* wk = (const float*)d_in[6],  *bk = (const float*)d_in[7];
    const float* wv = (const float*)d_in[8],  *bv = (const float*)d_in[9];
    const float* fcw = (const float*)d_in[10], *fcb = (const float*)d_in[11];
    const float* f1w = (const float*)d_in[12], *f1b = (const float*)d_in[13];
    const float* f2w = (const float*)d_in[14], *f2b_ = (const float*)d_in[15];
    const float* h1w = (const float*)d_in[16], *h1b = (const float*)d_in[17];
    const float* bng = (const float*)d_in[18], *bnb = (const float*)d_in[19];
    const float* bnm = (const float*)d_in[20], *bnv = (const float*)d_in[21];
    const float* h2w = (const float*)d_in[22], *h2b = (const float*)d_in[23];
    float* out = (float*)d_out;
    float* ws = (float*)d_ws;

    // workspace layout (float units)
    const size_t O_PE   = 0;                        // 262,144
    const size_t O_EMBT = O_PE + 262144;            // 3,840,000 (bf16 30000x256)
    const size_t O_X0B  = O_EMBT + 3840000;         // 2,097,152
    const size_t O_Q    = O_X0B + 2097152;          // 2,097,152
    const size_t O_K    = O_Q + 2097152;            // 2,097,152
    const size_t O_V    = O_K + 2097152;            // 2,097,152
    const size_t O_ATT  = O_V + 2097152;            // 2,097,152
    const size_t O_X1B  = O_ATT + 2097152;          // 2,097,152
    const size_t O_HB   = O_X1B + 2097152;          // 2,097,152
    const size_t O_OP   = O_HB + 2097152;           // 4,194,304 (bf16 4096x2048)
    const size_t O_ML   = O_OP + 4194304;           // 131,072 (f32 4096x32)
    const size_t O_WQKV = O_ML + 262144;            // 98,304 (768x256 shorts)
    const size_t O_WB3  = O_WQKV + 98304;           // 98,304
    const size_t O_B768 = O_WB3 + 98304;            // 768
    const size_t O_PART = O_B768 + 768;             // 131,072 (16x32x256 f32)
    const size_t O_SPAN = O_PART + 131072;

    float* pe   = ws + O_PE;
    unsigned short* embT = (unsigned short*)(ws + O_EMBT);
    unsigned short* x0b  = (unsigned short*)(ws + O_X0B);
    unsigned short* Qb   = (unsigned short*)(ws + O_Q);
    unsigned short* Kb   = (unsigned short*)(ws + O_K);
    unsigned short* Vt   = (unsigned short*)(ws + O_V);
    unsigned short* attb = (unsigned short*)(ws + O_ATT);
    unsigned short* x1b  = (unsigned short*)(ws + O_X1B);
    unsigned short* hb   = (unsigned short*)(ws + O_HB);
    unsigned short* Op   = (unsigned short*)(ws + O_OP);
    float* Lp   = ws + O_ML;
    unsigned short* wqkv = (unsigned short*)(ws + O_WQKV);
    unsigned short* wb3  = (unsigned short*)(ws + O_WB3);
    float* bias768 = ws + O_B768;
    float* part = ws + O_PART;
    int* spans  = (int*)(ws + O_SPAN);

    dim3 tb(32, 8);
    prologue_kernel<<<1617, 256, 0, stream>>>(amask, spans, pe,
                                              wq, wk, wv, bq, bk, bv, wqkv, bias768,
                                              fcw, f1w, f2w, wb3);
    transpose_b<<<dim3((VOCAB + 31) / 32, 8), tb, 0, stream>>>(emb_W, emb_b, embT);
    embed_kernel<<<MROWS, 256, 0, stream>>>(ids, embT, pe, x0b);

    // fused QKV: N=768, BM=64 -> grid (6,256)
    bgemm<5><<<dim3(6, 256), 256, 0, stream>>>(x0b, wqkv, bias768, nullptr, Qb, Kb, Vt);

    attn_split<<<1024, 256, 0, stream>>>(Qb, Kb, Vt, spans, Op, Lp);
    attn_combine<<<2048, 64, 0, stream>>>(Op, Lp, attb);

    dim3 gg(2, 256);
    bgemm<2><<<gg, 256, 0, stream>>>(attb, wb3 + 0 * 65536, fcb, x0b, x1b, nullptr, nullptr);
    bgemm<3><<<gg, 256, 0, stream>>>(x1b,  wb3 + 1 * 65536, f1b, nullptr, hb, nullptr, nullptr);
    bgemm<0><<<gg, 256, 0, stream>>>(hb,   wb3 + 2 * 65536, f2b_, nullptr, part, nullptr, nullptr);

    head2_kernel<<<BATCH, 128, 0, stream>>>(part, h1w, h1b, bng, bnb, bnm, bnv, h2w, h2b, out);
}

// Round 9
// 152.929 us; speedup vs baseline: 1.5917x; 1.0538x over previous
//
#include <hip/hip_runtime.h>
#include <math.h>

#define VOCAB 30000
#define DMODEL 256
#define NHEAD 4
#define SEQ 1024
#define BATCH 16
#define MROWS (BATCH*SEQ)   // 16384
#define SL2 0.18033688011112042f            // 0.125 * log2(e)
#define NEG2 (-1.4426950408889634e10f)      // -1e10 * log2(e)

typedef __attribute__((ext_vector_type(8))) short bf16x8;
typedef __attribute__((ext_vector_type(4))) float f32x4;

#if __has_builtin(__builtin_amdgcn_exp2f)
#define EXP2F __builtin_amdgcn_exp2f
#else
#define EXP2F exp2f
#endif

__device__ __forceinline__ unsigned short f2b(float f) {
    unsigned int u = __float_as_uint(f);
    unsigned int r = (u + 0x7FFFu + ((u >> 16) & 1u)) >> 16;
    return (unsigned short)r;
}
__device__ __forceinline__ unsigned short f2b_trunc(float f) {
    return (unsigned short)(__float_as_uint(f) >> 16);
}
__device__ __forceinline__ float b2f(unsigned short s) {
    unsigned int u = ((unsigned int)s) << 16;
    return __uint_as_float(u);
}

// ---------------- transpose W (D x V) -> bf16 embT (V x D), emb_b folded ----------------
__global__ void transpose_b(const float* __restrict__ in, const float* __restrict__ eb,
                            unsigned short* __restrict__ outb) {
    __shared__ float t[32][33];
    int c0 = blockIdx.x * 32, r0 = blockIdx.y * 32;   // c: vocab, r: d
    int tx = threadIdx.x, ty = threadIdx.y;           // 32 x 8
    for (int i = 0; i < 32; i += 8) {
        int r = r0 + ty + i, c = c0 + tx;
        if (c < VOCAB) t[ty + i][tx] = in[(size_t)r * VOCAB + c];
    }
    __syncthreads();
    float ebv = eb[r0 + tx];
    for (int i = 0; i < 32; i += 8) {
        int c = c0 + ty + i, r = r0 + tx;
        if (c < VOCAB) outb[(size_t)c * DMODEL + r] = f2b(t[tx][ty + i] + ebv);
    }
}

// ---------------- merged prologue: pe (64) | span (16) | cvt_qkv (769) | cvt3 (768) ----------------
__global__ void prologue_kernel(const int* __restrict__ mask, int* __restrict__ spans,
                                float* __restrict__ pe,
                                const float* __restrict__ wq, const float* __restrict__ wk,
                                const float* __restrict__ wv, const float* __restrict__ bq,
                                const float* __restrict__ bk, const float* __restrict__ bv,
                                unsigned short* __restrict__ wqkv, float* __restrict__ bias768,
                                const float* __restrict__ fcw, const float* __restrict__ f1w,
                                const float* __restrict__ f2w, unsigned short* __restrict__ wb3) {
    int blk = blockIdx.x;
    int t = threadIdx.x;
    if (blk < 64) {
        __shared__ double down[128];
        if (t < 128) down[t] = exp((double)(2 * t) * (-9.210340371976184 / 256.0));
        __syncthreads();
        int d2 = t & 127, half = t >> 7;
        #pragma unroll
        for (int i = 0; i < 8; i++) {
            int n = blk * 16 + half * 8 + i;
            double ang = (double)n * down[d2];
            pe[n * DMODEL + 2 * d2]     = (float)(sin(ang) * 0.1);
            pe[n * DMODEL + 2 * d2 + 1] = (float)(cos(ang) * 0.1);
        }
    } else if (blk < 80) {
        int b = blk - 64;
        __shared__ int smin, smax;
        if (t == 0) { smin = SEQ; smax = -1; }
        __syncthreads();
        int lmin = SEQ, lmax = -1;
        for (int i = t; i < SEQ; i += 256) {
            if (mask[b * SEQ + i] != 0) { lmin = min(lmin, i); lmax = max(lmax, i); }
        }
        atomicMin(&smin, lmin);
        atomicMax(&smax, lmax);
        __syncthreads();
        if (t == 0) {
            int st, en;
            if (smax < 0) { st = 0; en = SEQ - 1; }
            else          { st = smin; en = smax; }
            spans[b * 2] = st; spans[b * 2 + 1] = en;
        }
    } else if (blk < 849) {
        int cb = blk - 80;
        if (cb < 768) {
            const float* src = (cb < 256) ? wq : (cb < 512) ? wk : wv;
            wqkv[cb * 256 + t] = f2b(src[(cb & 255) * 256 + t]);
        } else {
            for (int j = t; j < 768; j += 256)
                bias768[j] = (j < 256) ? bq[j] : (j < 512) ? bk[j - 256] : bv[j - 512];
        }
    } else {
        int cb = blk - 849;
        const float* src = (cb < 256) ? fcw : (cb < 512) ? f1w : f2w;
        wb3[cb * 256 + t] = f2b(src[(cb & 255) * 256 + t]);
    }
}

// ---------------- embedding gather (coalesced bf16 rows) + pos enc ----------------
__global__ void embed_kernel(const int* __restrict__ ids, const unsigned short* __restrict__ embT,
                             const float* __restrict__ pe, unsigned short* __restrict__ x0b) {
    int bn = blockIdx.x;
    int d = threadIdx.x;
    int id = ids[bn];
    int n = bn & (SEQ - 1);
    float v = b2f(embT[(size_t)id * DMODEL + d]) + pe[n * DMODEL + d];
    x0b[(size_t)bn * DMODEL + d] = f2b(v);
}

// ---------------- fused QKV GEMM: A-tile resident in LDS, nb loop over {Q,K,V} ----------------
// 256 blocks x 512 threads; block owns 64 rows; Q scaled by SL2; V transposed scatter.
__global__ __launch_bounds__(512) void qkv_kernel(const unsigned short* __restrict__ A,
                                                  const unsigned short* __restrict__ W,
                                                  const float* __restrict__ bias,
                                                  unsigned short* __restrict__ Qb,
                                                  unsigned short* __restrict__ Kb,
                                                  unsigned short* __restrict__ Vt) {
    __shared__ unsigned short XA[4 * 64 * 64];   // 4 k-chunks of [64][128B], swizzled
    __shared__ unsigned short Bs[256 * 64];      // [256 n-rows][128B], swizzled
    int tid = threadIdx.x;
    int m0 = blockIdx.x * 64;
    int w = tid >> 6, l = tid & 63;
    int wrow = w >> 1, wcol = w & 1;
    int lg = l >> 4, ll = l & 15;
    int bb = m0 >> 10;

    #pragma unroll
    for (int i = 0; i < 4; i++) {
        int s = tid + i * 512;
        int row = s >> 5;                 // 0..63
        int kb = (s & 31) * 16;           // byte in 512B row
        int kt = kb >> 7, within = kb & 127;
        int swz = within ^ ((row & 7) << 4);
        float4 av = *(const float4*)((const char*)A + (size_t)(m0 + row) * 512 + kb);
        *(float4*)((char*)XA + kt * 8192 + row * 128 + swz) = av;
    }

    for (int nb = 0; nb < 3; nb++) {
        f32x4 acc[8] = {};
        for (int kt = 0; kt < 4; kt++) {
            __syncthreads();
            #pragma unroll
            for (int i = 0; i < 4; i++) {
                int s = tid + i * 512;
                int row = s >> 3;             // 0..255
                int kb = (s & 7) * 16;
                int swz = kb ^ ((row & 7) << 4);
                float4 bv = *(const float4*)((const char*)W + (size_t)(nb * 256 + row) * 512 + kt * 128 + kb);
                *(float4*)((char*)Bs + row * 128 + swz) = bv;
            }
            __syncthreads();
            int arow = wrow * 16 + ll;
            bf16x8 af[2];
            #pragma unroll
            for (int ks = 0; ks < 2; ks++)
                af[ks] = *(const bf16x8*)((const char*)XA + kt * 8192 + arow * 128 + ((lg * 16 + ks * 64) ^ ((arow & 7) << 4)));
            #pragma unroll
            for (int nf = 0; nf < 8; nf++) {
                int brow = wcol * 128 + nf * 16 + ll;
                #pragma unroll
                for (int ks = 0; ks < 2; ks++) {
                    bf16x8 bf = *(const bf16x8*)((const char*)Bs + brow * 128 + ((lg * 16 + ks * 64) ^ ((brow & 7) << 4)));
                    acc[nf] = __builtin_amdgcn_mfma_f32_16x16x32_bf16(af[ks], bf, acc[nf], 0, 0, 0);
                }
            }
        }
        // epilogue for this nb (0=Q,1=K,2=V)
        #pragma unroll
        for (int nf = 0; nf < 8; nf++) {
            int col = wcol * 128 + nf * 16 + ll;      // 0..255
            float bv = bias[nb * 256 + col];
            int hh = col >> 6, dk = col & 63;
            if (nb == 2) {
                unsigned int lo = (unsigned int)f2b(acc[nf][0]+ bv) | ((unsigned int)f2b(acc[nf][1]+bv) << 16);
                unsigned int hi = (unsigned int)f2b(acc[nf][2]+ bv) | ((unsigned int)f2b(acc[nf][3]+bv) << 16);
                int ns = (m0 & 1023) + wrow * 16 + lg * 4;
                unsigned int* dst = (unsigned int*)(Vt + ((((size_t)bb * 4 + hh) * 64) + dk) * 1024 + ns);
                dst[0] = lo;
                dst[1] = hi;
            } else {
                #pragma unroll
                for (int r2 = 0; r2 < 4; r2++) {
                    int ns = (m0 & 1023) + wrow * 16 + lg * 4 + r2;
                    float v = acc[nf][r2] + bv;
                    if (nb == 0)
                        Qb[((((size_t)bb * 4 + hh) * 1024) + ns) * 64 + dk] = f2b(v * SL2);
                    else
                        Kb[((((size_t)bb * 4 + hh) * 1024) + ns) * 64 + dk] = f2b(v);
                }
            }
        }
    }
}

// ---------------- split-KV flash attention, 4 waves/block, col-mask via acc init ----------------
__global__ __launch_bounds__(256) void attn_split(const unsigned short* __restrict__ Qb,
                                                  const unsigned short* __restrict__ Kb,
                                                  const unsigned short* __restrict__ Vt,
                                                  const int* __restrict__ spans,
                                                  unsigned short* __restrict__ Op,
                                                  float* __restrict__ Lp) {
    __shared__ __align__(16) unsigned short Ps[4][32 * 72];
    int tid = threadIdx.x;
    int w = tid >> 6, l = tid & 63;
    int id = blockIdx.x;               // 0..1023
    int c = id & 7, j = id >> 3;
    int bh = c * 8 + (j >> 4);
    int rem = j & 15;
    int qb = rem * 2 + (w >> 1);
    int sp = w & 1;
    int q0 = qb * 32;
    int b = bh >> 2;
    int lg = l >> 4, ll = l & 15;
    const char* Kp = (const char*)(Kb + (size_t)bh * SEQ * 64);
    const char* Vp = (const char*)(Vt + (size_t)bh * 64 * SEQ);
    const unsigned short* Qp = Qb + (size_t)bh * SEQ * 64;
    int start = spans[b * 2], end = spans[b * 2 + 1];

    bf16x8 qf[2][2];
    #pragma unroll
    for (int mf = 0; mf < 2; mf++)
        #pragma unroll
        for (int ks = 0; ks < 2; ks++)
            qf[mf][ks] = *(const bf16x8*)(Qp + (size_t)(q0 + mf * 16 + ll) * 64 + lg * 8 + ks * 32);

    bf16x8 ones;
    #pragma unroll
    for (int i = 0; i < 8; i++) ones[i] = (short)0x3F80;   // bf16 1.0

    f32x4 o[2][4] = {};
    f32x4 accl[2] = {};
    bool rowok[2][4];
    #pragma unroll
    for (int mf = 0; mf < 2; mf++)
        #pragma unroll
        for (int r2 = 0; r2 < 4; r2++) {
            int rr = q0 + mf * 16 + lg * 4 + r2;
            rowok[mf][r2] = (rr >= start) && (rr < end);
        }

    const char* kbase = Kp + (size_t)ll * 128 + lg * 16;
    const char* vbase = Vp + (size_t)ll * 2048 + lg * 16;

    for (int ct = 0; ct < 8; ct++) {
        int kv0 = sp * 512 + ct * 64;

        bf16x8 kf[4][2], vf[4][2];
        #pragma unroll
        for (int nf = 0; nf < 4; nf++)
            #pragma unroll
            for (int ks = 0; ks < 2; ks++)
                kf[nf][ks] = *(const bf16x8*)(kbase + (size_t)kv0 * 128 + nf * 2048 + ks * 64);
        #pragma unroll
        for (int cf = 0; cf < 4; cf++)
            #pragma unroll
            for (int ks = 0; ks < 2; ks++)
                vf[cf][ks] = *(const bf16x8*)(vbase + (size_t)cf * 32768 + kv0 * 2 + ks * 64);

        // column mask folded into accumulator init: s = (colok ? 0 : NEG2) + q.k
        f32x4 s[2][4];
        #pragma unroll
        for (int nf = 0; nf < 4; nf++) {
            int cc = kv0 + nf * 16 + ll;
            float ci = ((cc >= start) && (cc < end)) ? 0.f : NEG2;
            f32x4 cv = { ci, ci, ci, ci };
            s[0][nf] = cv; s[1][nf] = cv;
        }
        #pragma unroll
        for (int ks = 0; ks < 2; ks++)
            #pragma unroll
            for (int mf = 0; mf < 2; mf++)
                #pragma unroll
                for (int nf = 0; nf < 4; nf++)
                    s[mf][nf] = __builtin_amdgcn_mfma_f32_16x16x32_bf16(qf[mf][ks], kf[nf][ks], s[mf][nf], 0, 0, 0);

        #pragma unroll
        for (int mf = 0; mf < 2; mf++)
            #pragma unroll
            for (int nf = 0; nf < 4; nf++)
                #pragma unroll
                for (int r2 = 0; r2 < 4; r2++) {
                    float sv = rowok[mf][r2] ? s[mf][nf][r2] : 0.f;
                    s[mf][nf][r2] = EXP2F(sv);
                }

        // P -> per-wave LDS slice (bf16 trunc) for A-fragment relayout
        #pragma unroll
        for (int mf = 0; mf < 2; mf++)
            #pragma unroll
            for (int nf = 0; nf < 4; nf++)
                #pragma unroll
                for (int r2 = 0; r2 < 4; r2++)
                    Ps[w][(mf * 16 + lg * 4 + r2) * 72 + nf * 16 + ll] = f2b_trunc(s[mf][nf][r2]);

        bf16x8 pa[2][2];
        #pragma unroll
        for (int rf = 0; rf < 2; rf++) {
            int row = rf * 16 + ll;
            #pragma unroll
            for (int ks = 0; ks < 2; ks++)
                pa[rf][ks] = *(const bf16x8*)(&Ps[w][row * 72 + lg * 8 + ks * 32]);
        }
        #pragma unroll
        for (int ks = 0; ks < 2; ks++)
            #pragma unroll
            for (int rf = 0; rf < 2; rf++) {
                #pragma unroll
                for (int cf = 0; cf < 4; cf++)
                    o[rf][cf] = __builtin_amdgcn_mfma_f32_16x16x32_bf16(pa[rf][ks], vf[cf][ks], o[rf][cf], 0, 0, 0);
                accl[rf] = __builtin_amdgcn_mfma_f32_16x16x32_bf16(pa[rf][ks], ones, accl[rf], 0, 0, 0);
            }
    }

    size_t idx = ((size_t)(bh * 32 + qb)) * 2 + sp;
    #pragma unroll
    for (int rf = 0; rf < 2; rf++)
        #pragma unroll
        for (int r2 = 0; r2 < 4; r2++) {
            int rl = rf * 16 + lg * 4 + r2;
            #pragma unroll
            for (int cf = 0; cf < 4; cf++)
                Op[idx * 2048 + rl * 64 + cf * 16 + ll] = f2b(o[rf][cf][r2]);
            if (ll == 0)
                Lp[idx * 32 + rl] = accl[rf][r2];
        }
}

// ---------------- combine 2 splits: (o1+o2)/(l1+l2) -> attb (B,N,256) bf16 ----------------
__global__ __launch_bounds__(64) void attn_combine(const unsigned short* __restrict__ Op,
                                                   const float* __restrict__ Lp,
                                                   unsigned short* __restrict__ attb) {
    int cid = blockIdx.x;              // bh*32 + qb
    int bh = cid >> 5, qb = cid & 31;
    int b = bh >> 2, h = bh & 3;
    int t = threadIdx.x;
    int r = t >> 1, half = (t & 1) * 32;
    size_t i0 = (size_t)cid * 2;
    float l1 = Lp[i0 * 32 + r];
    float l2 = Lp[(i0 + 1) * 32 + r];
    float inv = 1.f / (l1 + l2);
    const unsigned short* p1 = Op + i0 * 2048 + (size_t)r * 64 + half;
    const unsigned short* p2 = Op + (i0 + 1) * 2048 + (size_t)r * 64 + half;
    unsigned short* po = attb + ((size_t)b * SEQ + qb * 32 + r) * 256 + h * 64 + half;
    #pragma unroll
    for (int c = 0; c < 4; c++) {
        bf16x8 a = *(const bf16x8*)(p1 + c * 8);
        bf16x8 bb = *(const bf16x8*)(p2 + c * 8);
        bf16x8 res;
        #pragma unroll
        for (int jj = 0; jj < 8; jj++)
            res[jj] = (short)f2b((b2f((unsigned short)a[jj]) + b2f((unsigned short)bb[jj])) * inv);
        *(bf16x8*)(po + c * 8) = res;
    }
}

// ---------------- fused FFN chain: x1=attb@fc^T+fcb+x0 ; h=gelu(x1@f1^T+f1b) ; pool(x2) ----------------
// 256 blocks x 512 threads; block owns 64 rows; x1,h stay in LDS.
__global__ __launch_bounds__(512) void ffn_kernel(const unsigned short* __restrict__ attb,
                                                  const unsigned short* __restrict__ x0b,
                                                  const unsigned short* __restrict__ W3,
                                                  const float* __restrict__ fcb,
                                                  const float* __restrict__ f1b,
                                                  const float* __restrict__ f2bv,
                                                  float* __restrict__ part) {
    __shared__ unsigned short BufA[4 * 64 * 64];   // attb staged -> later h
    __shared__ unsigned short BufB[4 * 64 * 64];   // x1
    __shared__ unsigned short Bs[256 * 64];
    int tid = threadIdx.x;
    int m0 = blockIdx.x * 64;
    int w = tid >> 6, l = tid & 63;
    int wrow = w >> 1, wcol = w & 1;
    int lg = l >> 4, ll = l & 15;
    int arow = wrow * 16 + ll;

    // stage attb -> BufA
    #pragma unroll
    for (int i = 0; i < 4; i++) {
        int s = tid + i * 512;
        int row = s >> 5;
        int kb = (s & 31) * 16;
        int kt = kb >> 7, within = kb & 127;
        int swz = within ^ ((row & 7) << 4);
        float4 av = *(const float4*)((const char*)attb + (size_t)(m0 + row) * 512 + kb);
        *(float4*)((char*)BufA + kt * 8192 + row * 128 + swz) = av;
    }

    #pragma unroll
    for (int phase = 0; phase < 3; phase++) {
        const unsigned short* Wp = W3 + phase * 65536;
        const char* Asrc = (phase == 1) ? (const char*)BufB : (const char*)BufA;
        f32x4 acc[8] = {};
        for (int kt = 0; kt < 4; kt++) {
            __syncthreads();
            #pragma unroll
            for (int i = 0; i < 4; i++) {
                int s = tid + i * 512;
                int row = s >> 3;
                int kb = (s & 7) * 16;
                int swz = kb ^ ((row & 7) << 4);
                float4 bv = *(const float4*)((const char*)Wp + (size_t)row * 512 + kt * 128 + kb);
                *(float4*)((char*)Bs + row * 128 + swz) = bv;
            }
            __syncthreads();
            bf16x8 af[2];
            #pragma unroll
            for (int ks = 0; ks < 2; ks++)
                af[ks] = *(const bf16x8*)(Asrc + kt * 8192 + arow * 128 + ((lg * 16 + ks * 64) ^ ((arow & 7) << 4)));
            #pragma unroll
            for (int nf = 0; nf < 8; nf++) {
                int brow = wcol * 128 + nf * 16 + ll;
                #pragma unroll
                for (int ks = 0; ks < 2; ks++) {
                    bf16x8 bf = *(const bf16x8*)((const char*)Bs + brow * 128 + ((lg * 16 + ks * 64) ^ ((brow & 7) << 4)));
                    acc[nf] = __builtin_amdgcn_mfma_f32_16x16x32_bf16(af[ks], bf, acc[nf], 0, 0, 0);
                }
            }
        }

        if (phase == 0) {
            // x1_raw = acc + fcb -> BufB (scalar b16, swizzled As-format)
            #pragma unroll
            for (int nf = 0; nf < 8; nf++) {
                int col = wcol * 128 + nf * 16 + ll;
                float bv = fcb[col];
                int kt = col >> 6;
                int byteoff = (2 * (col & 63));
                #pragma unroll
                for (int r2 = 0; r2 < 4; r2++) {
                    int row = wrow * 16 + lg * 4 + r2;
                    *(unsigned short*)((char*)BufB + kt * 8192 + row * 128 + (byteoff ^ ((row & 7) << 4))) = f2b(acc[nf][r2] + bv);
                }
            }
            __syncthreads();
            // residual: BufB += x0b (vectorized, coalesced)
            #pragma unroll
            for (int i = 0; i < 4; i++) {
                int s = tid + i * 512;
                int row = s >> 5;
                int kb = (s & 31) * 16;
                int kt = kb >> 7, within = kb & 127;
                int swz = within ^ ((row & 7) << 4);
                bf16x8* dst = (bf16x8*)((char*)BufB + kt * 8192 + row * 128 + swz);
                bf16x8 xv = *dst;
                bf16x8 rv = *(const bf16x8*)((const char*)x0b + (size_t)(m0 + row) * 512 + kb);
                bf16x8 res;
                #pragma unroll
                for (int jj = 0; jj < 8; jj++)
                    res[jj] = (short)f2b(b2f((unsigned short)xv[jj]) + b2f((unsigned short)rv[jj]));
                *dst = res;
            }
        } else if (phase == 1) {
            // h = gelu(acc + f1b) -> BufA
            #pragma unroll
            for (int nf = 0; nf < 8; nf++) {
                int col = wcol * 128 + nf * 16 + ll;
                float bv = f1b[col];
                int kt = col >> 6;
                int byteoff = (2 * (col & 63));
                #pragma unroll
                for (int r2 = 0; r2 < 4; r2++) {
                    int row = wrow * 16 + lg * 4 + r2;
                    float v = acc[nf][r2] + bv;
                    v = 0.5f * v * (1.f + erff(v * 0.70710678118654752f));
                    *(unsigned short*)((char*)BufA + kt * 8192 + row * 128 + (byteoff ^ ((row & 7) << 4))) = f2b(v);
                }
            }
        } else {
            // pool-partial: sum 16 rows of (acc + f2b) per col
            int bb = m0 >> 10;
            int chunk = ((m0 & 1023) >> 4) + wrow;
            #pragma unroll
            for (int nf = 0; nf < 8; nf++) {
                int col = wcol * 128 + nf * 16 + ll;
                float s_ = acc[nf][0] + acc[nf][1] + acc[nf][2] + acc[nf][3];
                s_ += __shfl_xor(s_, 16);
                s_ += __shfl_xor(s_, 32);
                s_ += 16.f * f2bv[col];
                if (lg == 0)
                    part[((size_t)bb * 64 + chunk) * 256 + col] = s_;
            }
        }
    }
}

// ---------------- fused pool stage 2 + MLP head (eval BatchNorm) ----------------
__global__ __launch_bounds__(128) void head2_kernel(const float* __restrict__ part,
                                                    const float* __restrict__ h1_w, const float* __restrict__ h1_b,
                                                    const float* __restrict__ g, const float* __restrict__ be,
                                                    const float* __restrict__ mu, const float* __restrict__ var,
                                                    const float* __restrict__ h2_w, const float* __restrict__ h2_b,
                                                    float* __restrict__ out) {
    int b = blockIdx.x, j = threadIdx.x;
    __shared__ float pl[256];
    __shared__ float red[128];
    float s0 = 0.f, s1 = 0.f;
    for (int ch = 0; ch < 64; ch++) {
        s0 += part[((size_t)b * 64 + ch) * 256 + j];
        s1 += part[((size_t)b * 64 + ch) * 256 + j + 128];
    }
    pl[j] = s0 * (1.f / 1024.f);
    pl[j + 128] = s1 * (1.f / 1024.f);
    __syncthreads();
    float s = 0.f;
    for (int d = 0; d < 256; d++) s = fmaf(pl[d], h1_w[j * 256 + d], s);
    s += h1_b[j];
    s = (s - mu[j]) / sqrtf(var[j] + 1e-5f) * g[j] + be[j];
    s = fmaxf(s, 0.f);
    red[j] = s * h2_w[j];
    __syncthreads();
    for (int off = 64; off; off >>= 1) {
        if (j < off) red[j] += red[j + off];
        __syncthreads();
    }
    if (j == 0) out[b] = red[0] + h2_b[0];
}

// ---------------- launch ----------------
extern "C" void kernel_launch(void* const* d_in, const int* in_sizes, int n_in,
                              void* d_out, int out_size, void* d_ws, size_t ws_size,
                              hipStream_t stream) {
    (void)in_sizes; (void)n_in; (void)out_size; (void)ws_size;
    const int*   ids    = (const int*)d_in[0];
    const int*   amask  = (const int*)d_in[1];
    const float* emb_W  = (const float*)d_in[2];
    const float* emb_b  = (const float*)d_in[3];
    const float* wq = (const float*)d_in[4],  *bq = (const float*)d_in[5];
    const float* wk = (const float*)d_in[6],  *bk = (const float*)d_in[7];
    const float* wv = (const float*)d_in[8],  *bv = (const float*)d_in[9];
    const float* fcw = (const float*)d_in[10], *fcb = (const float*)d_in[11];
    const float* f1w = (const float*)d_in[12], *f1b = (const float*)d_in[13];
    const float* f2w = (const float*)d_in[14], *f2b_ = (const float*)d_in[15];
    const float* h1w = (const float*)d_in[16], *h1b = (const float*)d_in[17];
    const float* bng = (const float*)d_in[18], *bnb = (const float*)d_in[19];
    const float* bnm = (const float*)d_in[20], *bnv = (const float*)d_in[21];
    const float* h2w = (const float*)d_in[22], *h2b = (const float*)d_in[23];
    float* out = (float*)d_out;
    float* ws = (float*)d_ws;

    // workspace layout (float units)
    const size_t O_PE   = 0;                        // 262,144
    const size_t O_EMBT = O_PE + 262144;            // 3,840,000 (bf16 30000x256)
    const size_t O_X0B  = O_EMBT + 3840000;         // 2,097,152
    const size_t O_Q    = O_X0B + 2097152;          // 2,097,152
    const size_t O_K    = O_Q + 2097152;            // 2,097,152
    const size_t O_V    = O_K + 2097152;            // 2,097,152
    const size_t O_ATT  = O_V + 2097152;            // 2,097,152
    const size_t O_OP   = O_ATT + 2097152;          // 4,194,304 (bf16 4096x2048)
    const size_t O_ML   = O_OP + 4194304;           // 131,072 (f32 4096x32)
    const size_t O_WQKV = O_ML + 131072;            // 98,304 (768x256 shorts)
    const size_t O_WB3  = O_WQKV + 98304;           // 98,304
    const size_t O_B768 = O_WB3 + 98304;            // 768
    const size_t O_PART = O_B768 + 768;             // 262,144 (16x64x256 f32)
    const size_t O_SPAN = O_PART + 262144;

    float* pe   = ws + O_PE;
    unsigned short* embT = (unsigned short*)(ws + O_EMBT);
    unsigned short* x0b  = (unsigned short*)(ws + O_X0B);
    unsigned short* Qb   = (unsigned short*)(ws + O_Q);
    unsigned short* Kb   = (unsigned short*)(ws + O_K);
    unsigned short* Vt   = (unsigned short*)(ws + O_V);
    unsigned short* attb = (unsigned short*)(ws + O_ATT);
    unsigned short* Op   = (unsigned short*)(ws + O_OP);
    float* Lp   = ws + O_ML;
    unsigned short* wqkv = (unsigned short*)(ws + O_WQKV);
    unsigned short* wb3  = (unsigned short*)(ws + O_WB3);
    float* bias768 = ws + O_B768;
    float* part = ws + O_PART;
    int* spans  = (int*)(ws + O_SPAN);

    dim3 tb(32, 8);
    prologue_kernel<<<1617, 256, 0, stream>>>(amask, spans, pe,
                                              wq, wk, wv, bq, bk, bv, wqkv, bias768,
                                              fcw, f1w, f2w, wb3);
    transpose_b<<<dim3((VOCAB + 31) / 32, 8), tb, 0, stream>>>(emb_W, emb_b, embT);
    embed_kernel<<<MROWS, 256, 0, stream>>>(ids, embT, pe, x0b);

    qkv_kernel<<<256, 512, 0, stream>>>(x0b, wqkv, bias768, Qb, Kb, Vt);

    attn_split<<<1024, 256, 0, stream>>>(Qb, Kb, Vt, spans, Op, Lp);
    attn_combine<<<2048, 64, 0, stream>>>(Op, Lp, attb);

    ffn_kernel<<<256, 512, 0, stream>>>(attb, x0b, wb3, fcb, f1b, f2b_, part);

    head2_kernel<<<BATCH, 128, 0, stream>>>(part, h1w, h1b, bng, bnb, bnm, bnv, h2w, h2b, out);
}

// Round 10
// 118.566 us; speedup vs baseline: 2.0530x; 1.2898x over previous
//
#include <hip/hip_runtime.h>
#include <math.h>

#define VOCAB 30000
#define DMODEL 256
#define NHEAD 4
#define SEQ 1024
#define BATCH 16
#define MROWS (BATCH*SEQ)   // 16384
#define SL2 0.18033688011112042f            // 0.125 * log2(e)
#define NEG2 (-1.4426950408889634e10f)      // -1e10 * log2(e)

typedef __attribute__((ext_vector_type(8))) short bf16x8;
typedef __attribute__((ext_vector_type(4))) float f32x4;

#if __has_builtin(__builtin_amdgcn_exp2f)
#define EXP2F __builtin_amdgcn_exp2f
#else
#define EXP2F exp2f
#endif

__device__ __forceinline__ unsigned short f2b(float f) {
    unsigned int u = __float_as_uint(f);
    unsigned int r = (u + 0x7FFFu + ((u >> 16) & 1u)) >> 16;
    return (unsigned short)r;
}
__device__ __forceinline__ unsigned short f2b_trunc(float f) {
    return (unsigned short)(__float_as_uint(f) >> 16);
}
__device__ __forceinline__ float b2f(unsigned short s) {
    unsigned int u = ((unsigned int)s) << 16;
    return __uint_as_float(u);
}

// ---------------- transpose W (D x V) -> bf16 embT (V x D), emb_b folded ----------------
__global__ void transpose_b(const float* __restrict__ in, const float* __restrict__ eb,
                            unsigned short* __restrict__ outb) {
    __shared__ float t[32][33];
    int c0 = blockIdx.x * 32, r0 = blockIdx.y * 32;   // c: vocab, r: d
    int tx = threadIdx.x, ty = threadIdx.y;           // 32 x 8
    for (int i = 0; i < 32; i += 8) {
        int r = r0 + ty + i, c = c0 + tx;
        if (c < VOCAB) t[ty + i][tx] = in[(size_t)r * VOCAB + c];
    }
    __syncthreads();
    float ebv = eb[r0 + tx];
    for (int i = 0; i < 32; i += 8) {
        int c = c0 + ty + i, r = r0 + tx;
        if (c < VOCAB) outb[(size_t)c * DMODEL + r] = f2b(t[tx][ty + i] + ebv);
    }
}

// ---------------- merged prologue: pe (64) | span (16) | cvt_qkv (769) | cvt3 (768) ----------------
__global__ void prologue_kernel(const int* __restrict__ mask, int* __restrict__ spans,
                                float* __restrict__ pe,
                                const float* __restrict__ wq, const float* __restrict__ wk,
                                const float* __restrict__ wv, const float* __restrict__ bq,
                                const float* __restrict__ bk, const float* __restrict__ bv,
                                unsigned short* __restrict__ wqkv, float* __restrict__ bias768,
                                const float* __restrict__ fcw, const float* __restrict__ f1w,
                                const float* __restrict__ f2w, unsigned short* __restrict__ wb3) {
    int blk = blockIdx.x;
    int t = threadIdx.x;
    if (blk < 64) {
        __shared__ double down[128];
        if (t < 128) down[t] = exp((double)(2 * t) * (-9.210340371976184 / 256.0));
        __syncthreads();
        int d2 = t & 127, half = t >> 7;
        #pragma unroll
        for (int i = 0; i < 8; i++) {
            int n = blk * 16 + half * 8 + i;
            double ang = (double)n * down[d2];
            pe[n * DMODEL + 2 * d2]     = (float)(sin(ang) * 0.1);
            pe[n * DMODEL + 2 * d2 + 1] = (float)(cos(ang) * 0.1);
        }
    } else if (blk < 80) {
        int b = blk - 64;
        __shared__ int smin, smax;
        if (t == 0) { smin = SEQ; smax = -1; }
        __syncthreads();
        int lmin = SEQ, lmax = -1;
        for (int i = t; i < SEQ; i += 256) {
            if (mask[b * SEQ + i] != 0) { lmin = min(lmin, i); lmax = max(lmax, i); }
        }
        atomicMin(&smin, lmin);
        atomicMax(&smax, lmax);
        __syncthreads();
        if (t == 0) {
            int st, en;
            if (smax < 0) { st = 0; en = SEQ - 1; }
            else          { st = smin; en = smax; }
            spans[b * 2] = st; spans[b * 2 + 1] = en;
        }
    } else if (blk < 849) {
        int cb = blk - 80;
        if (cb < 768) {
            const float* src = (cb < 256) ? wq : (cb < 512) ? wk : wv;
            wqkv[cb * 256 + t] = f2b(src[(cb & 255) * 256 + t]);
        } else {
            for (int j = t; j < 768; j += 256)
                bias768[j] = (j < 256) ? bq[j] : (j < 512) ? bk[j - 256] : bv[j - 512];
        }
    } else {
        int cb = blk - 849;
        const float* src = (cb < 256) ? fcw : (cb < 512) ? f1w : f2w;
        wb3[cb * 256 + t] = f2b(src[(cb & 255) * 256 + t]);
    }
}

// ---------------- embedding gather (coalesced bf16 rows) + pos enc ----------------
__global__ void embed_kernel(const int* __restrict__ ids, const unsigned short* __restrict__ embT,
                             const float* __restrict__ pe, unsigned short* __restrict__ x0b) {
    int bn = blockIdx.x;
    int d = threadIdx.x;
    int id = ids[bn];
    int n = bn & (SEQ - 1);
    float v = b2f(embT[(size_t)id * DMODEL + d]) + pe[n * DMODEL + d];
    x0b[(size_t)bn * DMODEL + d] = f2b(v);
}

// ---------------- fused QKV GEMM: A-tile resident in LDS, nb loop over {Q,K,V} ----------------
__global__ __launch_bounds__(512) void qkv_kernel(const unsigned short* __restrict__ A,
                                                  const unsigned short* __restrict__ W,
                                                  const float* __restrict__ bias,
                                                  unsigned short* __restrict__ Qb,
                                                  unsigned short* __restrict__ Kb,
                                                  unsigned short* __restrict__ Vt) {
    __shared__ unsigned short XA[4 * 64 * 64];   // 4 k-chunks of [64][128B], swizzled
    __shared__ unsigned short Bs[256 * 64];      // [256 n-rows][128B], swizzled
    int tid = threadIdx.x;
    int m0 = blockIdx.x * 64;
    int w = tid >> 6, l = tid & 63;
    int wrow = w >> 1, wcol = w & 1;
    int lg = l >> 4, ll = l & 15;
    int bb = m0 >> 10;

    #pragma unroll
    for (int i = 0; i < 4; i++) {
        int s = tid + i * 512;
        int row = s >> 5;                 // 0..63
        int kb = (s & 31) * 16;           // byte in 512B row
        int kt = kb >> 7, within = kb & 127;
        int swz = within ^ ((row & 7) << 4);
        float4 av = *(const float4*)((const char*)A + (size_t)(m0 + row) * 512 + kb);
        *(float4*)((char*)XA + kt * 8192 + row * 128 + swz) = av;
    }

    for (int nb = 0; nb < 3; nb++) {
        f32x4 acc[8] = {};
        for (int kt = 0; kt < 4; kt++) {
            __syncthreads();
            #pragma unroll
            for (int i = 0; i < 4; i++) {
                int s = tid + i * 512;
                int row = s >> 3;             // 0..255
                int kb = (s & 7) * 16;
                int swz = kb ^ ((row & 7) << 4);
                float4 bv = *(const float4*)((const char*)W + (size_t)(nb * 256 + row) * 512 + kt * 128 + kb);
                *(float4*)((char*)Bs + row * 128 + swz) = bv;
            }
            __syncthreads();
            int arow = wrow * 16 + ll;
            bf16x8 af[2];
            #pragma unroll
            for (int ks = 0; ks < 2; ks++)
                af[ks] = *(const bf16x8*)((const char*)XA + kt * 8192 + arow * 128 + ((lg * 16 + ks * 64) ^ ((arow & 7) << 4)));
            #pragma unroll
            for (int nf = 0; nf < 8; nf++) {
                int brow = wcol * 128 + nf * 16 + ll;
                #pragma unroll
                for (int ks = 0; ks < 2; ks++) {
                    bf16x8 bf = *(const bf16x8*)((const char*)Bs + brow * 128 + ((lg * 16 + ks * 64) ^ ((brow & 7) << 4)));
                    acc[nf] = __builtin_amdgcn_mfma_f32_16x16x32_bf16(af[ks], bf, acc[nf], 0, 0, 0);
                }
            }
        }
        // epilogue for this nb (0=Q,1=K,2=V)
        #pragma unroll
        for (int nf = 0; nf < 8; nf++) {
            int col = wcol * 128 + nf * 16 + ll;      // 0..255
            float bv = bias[nb * 256 + col];
            int hh = col >> 6, dk = col & 63;
            if (nb == 2) {
                unsigned int lo = (unsigned int)f2b(acc[nf][0] + bv) | ((unsigned int)f2b(acc[nf][1] + bv) << 16);
                unsigned int hi = (unsigned int)f2b(acc[nf][2] + bv) | ((unsigned int)f2b(acc[nf][3] + bv) << 16);
                int ns = (m0 & 1023) + wrow * 16 + lg * 4;
                unsigned int* dst = (unsigned int*)(Vt + ((((size_t)bb * 4 + hh) * 64) + dk) * 1024 + ns);
                dst[0] = lo;
                dst[1] = hi;
            } else {
                #pragma unroll
                for (int r2 = 0; r2 < 4; r2++) {
                    int ns = (m0 & 1023) + wrow * 16 + lg * 4 + r2;
                    float v = acc[nf][r2] + bv;
                    if (nb == 0)
                        Qb[((((size_t)bb * 4 + hh) * 1024) + ns) * 64 + dk] = f2b(v * SL2);
                    else
                        Kb[((((size_t)bb * 4 + hh) * 1024) + ns) * 64 + dk] = f2b(v);
                }
            }
        }
    }
}

// ---------------- cooperative-block flash attention ----------------
// 512 blocks x 256 thr (4 waves). Block owns one (b,h) + 128 q-rows; waves share
// LDS-staged K/V tiles (loaded once per block). No KV split -> writes attb directly.
// No max tracking (log2-domain, m=0); l via MFMA ones-column; col mask in acc-init.
__global__ __launch_bounds__(256) void attn_coop(const unsigned short* __restrict__ Qb,
                                                 const unsigned short* __restrict__ Kb,
                                                 const unsigned short* __restrict__ Vt,
                                                 const int* __restrict__ spans,
                                                 unsigned short* __restrict__ attb) {
    __shared__ unsigned short Ks[64 * 64];     // [kv 64][128B] swizzled
    __shared__ unsigned short Vs[64 * 64];     // [d 64][128B of kv] swizzled
    __shared__ __align__(16) unsigned short Ps[4][32 * 72];
    int tid = threadIdx.x;
    int w = tid >> 6, l = tid & 63;
    int id = blockIdx.x;               // 0..511
    int c = id & 7, rest = id >> 3;    // c: XCD class
    int bh = c * 8 + (rest >> 3);
    int qg = rest & 7;
    int q0 = qg * 128 + w * 32;
    int b = bh >> 2, h = bh & 3;
    int lg = l >> 4, ll = l & 15;
    const char* Kp = (const char*)(Kb + (size_t)bh * SEQ * 64);
    const char* Vp = (const char*)(Vt + (size_t)bh * 64 * SEQ);
    const unsigned short* Qp = Qb + (size_t)bh * SEQ * 64;
    int start = spans[b * 2], end = spans[b * 2 + 1];

    bf16x8 qf[2][2];
    #pragma unroll
    for (int mf = 0; mf < 2; mf++)
        #pragma unroll
        for (int ks = 0; ks < 2; ks++)
            qf[mf][ks] = *(const bf16x8*)(Qp + (size_t)(q0 + mf * 16 + ll) * 64 + lg * 8 + ks * 32);

    bf16x8 ones;
    #pragma unroll
    for (int i = 0; i < 8; i++) ones[i] = (short)0x3F80;   // bf16 1.0

    f32x4 o[2][4] = {};
    f32x4 accl[2] = {};
    bool rowok[2][4];
    #pragma unroll
    for (int mf = 0; mf < 2; mf++)
        #pragma unroll
        for (int r2 = 0; r2 < 4; r2++) {
            int rr = q0 + mf * 16 + lg * 4 + r2;
            rowok[mf][r2] = (rr >= start) && (rr < end);
        }

    for (int ct = 0; ct < 16; ct++) {
        int kv0 = ct * 64;

        // cooperative stage: K tile (8KB) + V tile (8KB), swizzled
        #pragma unroll
        for (int i = 0; i < 2; i++) {
            int s = tid + i * 256;         // 0..511
            int row = s >> 3;              // 0..63
            int kb = (s & 7) * 16;
            int swz = kb ^ ((row & 7) << 4);
            float4 kvv = *(const float4*)(Kp + (size_t)(kv0 + row) * 128 + kb);
            *(float4*)((char*)Ks + row * 128 + swz) = kvv;
            float4 vvv = *(const float4*)(Vp + (size_t)row * 2048 + kv0 * 2 + kb);
            *(float4*)((char*)Vs + row * 128 + swz) = vvv;
        }
        __syncthreads();

        // column mask folded into accumulator init
        f32x4 s[2][4];
        #pragma unroll
        for (int nf = 0; nf < 4; nf++) {
            int cc = kv0 + nf * 16 + ll;
            float ci = ((cc >= start) && (cc < end)) ? 0.f : NEG2;
            f32x4 cv = { ci, ci, ci, ci };
            s[0][nf] = cv; s[1][nf] = cv;
        }
        #pragma unroll
        for (int ks = 0; ks < 2; ks++)
            #pragma unroll
            for (int nf = 0; nf < 4; nf++) {
                int row = nf * 16 + ll;
                bf16x8 kf = *(const bf16x8*)((const char*)Ks + row * 128 + ((lg * 16 + ks * 64) ^ ((row & 7) << 4)));
                #pragma unroll
                for (int mf = 0; mf < 2; mf++)
                    s[mf][nf] = __builtin_amdgcn_mfma_f32_16x16x32_bf16(qf[mf][ks], kf, s[mf][nf], 0, 0, 0);
            }

        #pragma unroll
        for (int mf = 0; mf < 2; mf++)
            #pragma unroll
            for (int nf = 0; nf < 4; nf++)
                #pragma unroll
                for (int r2 = 0; r2 < 4; r2++) {
                    float sv = rowok[mf][r2] ? s[mf][nf][r2] : 0.f;
                    s[mf][nf][r2] = EXP2F(sv);
                }

        // P -> per-wave LDS slice (bf16 trunc)
        #pragma unroll
        for (int mf = 0; mf < 2; mf++)
            #pragma unroll
            for (int nf = 0; nf < 4; nf++)
                #pragma unroll
                for (int r2 = 0; r2 < 4; r2++)
                    Ps[w][(mf * 16 + lg * 4 + r2) * 72 + nf * 16 + ll] = f2b_trunc(s[mf][nf][r2]);

        bf16x8 pa[2][2];
        #pragma unroll
        for (int rf = 0; rf < 2; rf++) {
            int row = rf * 16 + ll;
            #pragma unroll
            for (int ks = 0; ks < 2; ks++)
                pa[rf][ks] = *(const bf16x8*)(&Ps[w][row * 72 + lg * 8 + ks * 32]);
        }
        #pragma unroll
        for (int ks = 0; ks < 2; ks++)
            #pragma unroll
            for (int cf = 0; cf < 4; cf++) {
                int row = cf * 16 + ll;
                bf16x8 vf = *(const bf16x8*)((const char*)Vs + row * 128 + ((lg * 16 + ks * 64) ^ ((row & 7) << 4)));
                #pragma unroll
                for (int rf = 0; rf < 2; rf++)
                    o[rf][cf] = __builtin_amdgcn_mfma_f32_16x16x32_bf16(pa[rf][ks], vf, o[rf][cf], 0, 0, 0);
            }
        #pragma unroll
        for (int ks = 0; ks < 2; ks++)
            #pragma unroll
            for (int rf = 0; rf < 2; rf++)
                accl[rf] = __builtin_amdgcn_mfma_f32_16x16x32_bf16(pa[rf][ks], ones, accl[rf], 0, 0, 0);

        __syncthreads();   // all waves done reading Ks/Vs before next stage
    }

    // epilogue: normalize + store bf16 directly to attb (B,N,256)
    #pragma unroll
    for (int rf = 0; rf < 2; rf++)
        #pragma unroll
        for (int r2 = 0; r2 < 4; r2++) {
            float inv = 1.f / accl[rf][r2];
            int row = q0 + rf * 16 + lg * 4 + r2;
            #pragma unroll
            for (int cf = 0; cf < 4; cf++) {
                int dk = cf * 16 + ll;
                attb[((size_t)b * SEQ + row) * 256 + h * 64 + dk] = f2b(o[rf][cf][r2] * inv);
            }
        }
}

// ---------------- fused FFN chain: x1=attb@fc^T+fcb+x0 ; h=gelu(x1@f1^T+f1b) ; pool(x2) ----------------
__global__ __launch_bounds__(512) void ffn_kernel(const unsigned short* __restrict__ attb,
                                                  const unsigned short* __restrict__ x0b,
                                                  const unsigned short* __restrict__ W3,
                                                  const float* __restrict__ fcb,
                                                  const float* __restrict__ f1b,
                                                  const float* __restrict__ f2bv,
                                                  float* __restrict__ part) {
    __shared__ unsigned short BufA[4 * 64 * 64];   // attb staged -> later h
    __shared__ unsigned short BufB[4 * 64 * 64];   // x1
    __shared__ unsigned short Bs[256 * 64];
    int tid = threadIdx.x;
    int m0 = blockIdx.x * 64;
    int w = tid >> 6, l = tid & 63;
    int wrow = w >> 1, wcol = w & 1;
    int lg = l >> 4, ll = l & 15;
    int arow = wrow * 16 + ll;

    // stage attb -> BufA
    #pragma unroll
    for (int i = 0; i < 4; i++) {
        int s = tid + i * 512;
        int row = s >> 5;
        int kb = (s & 31) * 16;
        int kt = kb >> 7, within = kb & 127;
        int swz = within ^ ((row & 7) << 4);
        float4 av = *(const float4*)((const char*)attb + (size_t)(m0 + row) * 512 + kb);
        *(float4*)((char*)BufA + kt * 8192 + row * 128 + swz) = av;
    }

    #pragma unroll
    for (int phase = 0; phase < 3; phase++) {
        const unsigned short* Wp = W3 + phase * 65536;
        const char* Asrc = (phase == 1) ? (const char*)BufB : (const char*)BufA;
        f32x4 acc[8] = {};
        for (int kt = 0; kt < 4; kt++) {
            __syncthreads();
            #pragma unroll
            for (int i = 0; i < 4; i++) {
                int s = tid + i * 512;
                int row = s >> 3;
                int kb = (s & 7) * 16;
                int swz = kb ^ ((row & 7) << 4);
                float4 bv = *(const float4*)((const char*)Wp + (size_t)row * 512 + kt * 128 + kb);
                *(float4*)((char*)Bs + row * 128 + swz) = bv;
            }
            __syncthreads();
            bf16x8 af[2];
            #pragma unroll
            for (int ks = 0; ks < 2; ks++)
                af[ks] = *(const bf16x8*)(Asrc + kt * 8192 + arow * 128 + ((lg * 16 + ks * 64) ^ ((arow & 7) << 4)));
            #pragma unroll
            for (int nf = 0; nf < 8; nf++) {
                int brow = wcol * 128 + nf * 16 + ll;
                #pragma unroll
                for (int ks = 0; ks < 2; ks++) {
                    bf16x8 bf = *(const bf16x8*)((const char*)Bs + brow * 128 + ((lg * 16 + ks * 64) ^ ((brow & 7) << 4)));
                    acc[nf] = __builtin_amdgcn_mfma_f32_16x16x32_bf16(af[ks], bf, acc[nf], 0, 0, 0);
                }
            }
        }

        if (phase == 0) {
            #pragma unroll
            for (int nf = 0; nf < 8; nf++) {
                int col = wcol * 128 + nf * 16 + ll;
                float bv = fcb[col];
                int kt = col >> 6;
                int byteoff = (2 * (col & 63));
                #pragma unroll
                for (int r2 = 0; r2 < 4; r2++) {
                    int row = wrow * 16 + lg * 4 + r2;
                    *(unsigned short*)((char*)BufB + kt * 8192 + row * 128 + (byteoff ^ ((row & 7) << 4))) = f2b(acc[nf][r2] + bv);
                }
            }
            __syncthreads();
            // residual: BufB += x0b
            #pragma unroll
            for (int i = 0; i < 4; i++) {
                int s = tid + i * 512;
                int row = s >> 5;
                int kb = (s & 31) * 16;
                int kt = kb >> 7, within = kb & 127;
                int swz = within ^ ((row & 7) << 4);
                bf16x8* dst = (bf16x8*)((char*)BufB + kt * 8192 + row * 128 + swz);
                bf16x8 xv = *dst;
                bf16x8 rv = *(const bf16x8*)((const char*)x0b + (size_t)(m0 + row) * 512 + kb);
                bf16x8 res;
                #pragma unroll
                for (int jj = 0; jj < 8; jj++)
                    res[jj] = (short)f2b(b2f((unsigned short)xv[jj]) + b2f((unsigned short)rv[jj]));
                *dst = res;
            }
        } else if (phase == 1) {
            #pragma unroll
            for (int nf = 0; nf < 8; nf++) {
                int col = wcol * 128 + nf * 16 + ll;
                float bv = f1b[col];
                int kt = col >> 6;
                int byteoff = (2 * (col & 63));
                #pragma unroll
                for (int r2 = 0; r2 < 4; r2++) {
                    int row = wrow * 16 + lg * 4 + r2;
                    float v = acc[nf][r2] + bv;
                    v = 0.5f * v * (1.f + erff(v * 0.70710678118654752f));
                    *(unsigned short*)((char*)BufA + kt * 8192 + row * 128 + (byteoff ^ ((row & 7) << 4))) = f2b(v);
                }
            }
        } else {
            int bb = m0 >> 10;
            int chunk = ((m0 & 1023) >> 4) + wrow;
            #pragma unroll
            for (int nf = 0; nf < 8; nf++) {
                int col = wcol * 128 + nf * 16 + ll;
                float s_ = acc[nf][0] + acc[nf][1] + acc[nf][2] + acc[nf][3];
                s_ += __shfl_xor(s_, 16);
                s_ += __shfl_xor(s_, 32);
                s_ += 16.f * f2bv[col];
                if (lg == 0)
                    part[((size_t)bb * 64 + chunk) * 256 + col] = s_;
            }
        }
    }
}

// ---------------- fused pool stage 2 + MLP head (eval BatchNorm) ----------------
__global__ __launch_bounds__(128) void head2_kernel(const float* __restrict__ part,
                                                    const float* __restrict__ h1_w, const float* __restrict__ h1_b,
                                                    const float* __restrict__ g, const float* __restrict__ be,
                                                    const float* __restrict__ mu, const float* __restrict__ var,
                                                    const float* __restrict__ h2_w, const float* __restrict__ h2_b,
                                                    float* __restrict__ out) {
    int b = blockIdx.x, j = threadIdx.x;
    __shared__ float pl[256];
    __shared__ float red[128];
    float s0 = 0.f, s1 = 0.f;
    for (int ch = 0; ch < 64; ch++) {
        s0 += part[((size_t)b * 64 + ch) * 256 + j];
        s1 += part[((size_t)b * 64 + ch) * 256 + j + 128];
    }
    pl[j] = s0 * (1.f / 1024.f);
    pl[j + 128] = s1 * (1.f / 1024.f);
    __syncthreads();
    float s = 0.f;
    for (int d = 0; d < 256; d++) s = fmaf(pl[d], h1_w[j * 256 + d], s);
    s += h1_b[j];
    s = (s - mu[j]) / sqrtf(var[j] + 1e-5f) * g[j] + be[j];
    s = fmaxf(s, 0.f);
    red[j] = s * h2_w[j];
    __syncthreads();
    for (int off = 64; off; off >>= 1) {
        if (j < off) red[j] += red[j + off];
        __syncthreads();
    }
    if (j == 0) out[b] = red[0] + h2_b[0];
}

// ---------------- launch ----------------
extern "C" void kernel_launch(void* const* d_in, const int* in_sizes, int n_in,
                              void* d_out, int out_size, void* d_ws, size_t ws_size,
                              hipStream_t stream) {
    (void)in_sizes; (void)n_in; (void)out_size; (void)ws_size;
    const int*   ids    = (const int*)d_in[0];
    const int*   amask  = (const int*)d_in[1];
    const float* emb_W  = (const float*)d_in[2];
    const float* emb_b  = (const float*)d_in[3];
    const float* wq = (const float*)d_in[4],  *bq = (const float*)d_in[5];
    const float* wk = (const float*)d_in[6],  *bk = (const float*)d_in[7];
    const float* wv = (const float*)d_in[8],  *bv = (const float*)d_in[9];
    const float* fcw = (const float*)d_in[10], *fcb = (const float*)d_in[11];
    const float* f1w = (const float*)d_in[12], *f1b = (const float*)d_in[13];
    const float* f2w = (const float*)d_in[14], *f2b_ = (const float*)d_in[15];
    const float* h1w = (const float*)d_in[16], *h1b = (const float*)d_in[17];
    const float* bng = (const float*)d_in[18], *bnb = (const float*)d_in[19];
    const float* bnm = (const float*)d_in[20], *bnv = (const float*)d_in[21];
    const float* h2w = (const float*)d_in[22], *h2b = (const float*)d_in[23];
    float* out = (float*)d_out;
    float* ws = (float*)d_ws;

    // workspace layout (float units)
    const size_t O_PE   = 0;                        // 262,144
    const size_t O_EMBT = O_PE + 262144;            // 3,840,000 (bf16 30000x256)
    const size_t O_X0B  = O_EMBT + 3840000;         // 2,097,152
    const size_t O_Q    = O_X0B + 2097152;          // 2,097,152
    const size_t O_K    = O_Q + 2097152;            // 2,097,152
    const size_t O_V    = O_K + 2097152;            // 2,097,152
    const size_t O_ATT  = O_V + 2097152;            // 2,097,152
    const size_t O_WQKV = O_ATT + 2097152;          // 98,304 (768x256 shorts)
    const size_t O_WB3  = O_WQKV + 98304;           // 98,304
    const size_t O_B768 = O_WB3 + 98304;            // 768
    const size_t O_PART = O_B768 + 768;             // 262,144 (16x64x256 f32)
    const size_t O_SPAN = O_PART + 262144;

    float* pe   = ws + O_PE;
    unsigned short* embT = (unsigned short*)(ws + O_EMBT);
    unsigned short* x0b  = (unsigned short*)(ws + O_X0B);
    unsigned short* Qb   = (unsigned short*)(ws + O_Q);
    unsigned short* Kb   = (unsigned short*)(ws + O_K);
    unsigned short* Vt   = (unsigned short*)(ws + O_V);
    unsigned short* attb = (unsigned short*)(ws + O_ATT);
    unsigned short* wqkv = (unsigned short*)(ws + O_WQKV);
    unsigned short* wb3  = (unsigned short*)(ws + O_WB3);
    float* bias768 = ws + O_B768;
    float* part = ws + O_PART;
    int* spans  = (int*)(ws + O_SPAN);

    dim3 tb(32, 8);
    prologue_kernel<<<1617, 256, 0, stream>>>(amask, spans, pe,
                                              wq, wk, wv, bq, bk, bv, wqkv, bias768,
                                              fcw, f1w, f2w, wb3);
    transpose_b<<<dim3((VOCAB + 31) / 32, 8), tb, 0, stream>>>(emb_W, emb_b, embT);
    embed_kernel<<<MROWS, 256, 0, stream>>>(ids, embT, pe, x0b);

    qkv_kernel<<<256, 512, 0, stream>>>(x0b, wqkv, bias768, Qb, Kb, Vt);

    attn_coop<<<512, 256, 0, stream>>>(Qb, Kb, Vt, spans, attb);

    ffn_kernel<<<256, 512, 0, stream>>>(attb, x0b, wb3, fcb, f1b, f2b_, part);

    head2_kernel<<<BATCH, 128, 0, stream>>>(part, h1w, h1b, bng, bnb, bnm, bnv, h2w, h2b, out);
}